// Round 1
// baseline (1027.623 us; speedup 1.0000x reference)
//
#include <hip/hip_runtime.h>
#include <math.h>

#define T_SEQ 1024
#define DM    1024
#define HTOT  64
#define NH16  16
#define DH    64
#define SILU_SCALE 1.8137993642342178f   // pi/sqrt(3)

__device__ __forceinline__ float softplusf(float x){
    float ax = fabsf(x);
    return fmaxf(x, 0.0f) + log1pf(expf(-ax));
}

// C[M,N] = A[M,K] @ B[K,N] + bias[N]; M,N multiples of 64, K multiple of 16
__global__ __launch_bounds__(256) void sgemm_kernel(
    const float* __restrict__ A, const float* __restrict__ B,
    const float* __restrict__ bias, float* __restrict__ C,
    int M, int N, int K)
{
    __shared__ float As[16][68];   // [k][m]
    __shared__ float Bs[16][68];   // [k][n]
    const int tid = threadIdx.x;
    const int tx = tid & 15;        // n-block
    const int ty = tid >> 4;        // m-block
    const int m0 = blockIdx.y * 64;
    const int n0 = blockIdx.x * 64;

    const int ar  = tid >> 2;         // 0..63 (A tile row)
    const int ac4 = (tid & 3) << 2;   // 0..12 (A tile col, x4)
    const int br  = tid >> 4;         // 0..15 (B tile row)
    const int bc4 = (tid & 15) << 2;  // 0..60 (B tile col, x4)

    float acc[4][4] = {};

    for (int k0 = 0; k0 < K; k0 += 16){
        float4 av = *(const float4*)&A[(size_t)(m0 + ar) * K + k0 + ac4];
        float4 bv = *(const float4*)&B[(size_t)(k0 + br) * N + n0 + bc4];
        As[ac4+0][ar] = av.x; As[ac4+1][ar] = av.y;
        As[ac4+2][ar] = av.z; As[ac4+3][ar] = av.w;
        *(float4*)&Bs[br][bc4] = bv;
        __syncthreads();
        #pragma unroll
        for (int kk = 0; kk < 16; kk++){
            float a[4], b[4];
            *(float4*)a = *(const float4*)&As[kk][ty << 2];
            *(float4*)b = *(const float4*)&Bs[kk][tx << 2];
            #pragma unroll
            for (int i = 0; i < 4; i++)
                #pragma unroll
                for (int j = 0; j < 4; j++)
                    acc[i][j] = fmaf(a[i], b[j], acc[i][j]);
        }
        __syncthreads();
    }
    #pragma unroll
    for (int i = 0; i < 4; i++){
        int row = m0 + (ty << 2) + i;
        #pragma unroll
        for (int j = 0; j < 4; j++){
            int col = n0 + (tx << 2) + j;
            C[(size_t)row * N + col] = acc[i][j] + bias[col];
        }
    }
}

// RoPE in-place on Q (1024 x 4096, 64 heads of 64). One thread per (t,h).
__global__ void rope_q_kernel(float* __restrict__ Q)
{
    int idx = blockIdx.x * blockDim.x + threadIdx.x;   // 65536
    int t = idx >> 6, h = idx & 63;
    float* p = Q + (size_t)t * (HTOT * DH) + h * DH;
    float x[64], o[64];
    #pragma unroll
    for (int i = 0; i < 16; i++) *(float4*)&x[i*4] = *(const float4*)(p + i*4);
    #pragma unroll
    for (int d = 0; d < 32; d++){
        float inv = expf(-(float)d * 0.28782313662425575f);  // ln(1e4)/32
        float ang = (float)t * inv;
        float s, c; sincosf(ang, &s, &c);
        float x1 = x[2*d], x2 = x[2*d+1];
        o[d]      = x1 * c - x2 * s;
        o[d + 32] = x1 * s + x2 * c;
    }
    #pragma unroll
    for (int i = 0; i < 16; i++) *(float4*)(p + i*4) = *(float4*)&o[i*4];
}

// RoPE in-place on K (1024 x 1024, 16 heads of 64) + per-key norm denom.
__global__ void rope_k_kernel(float* __restrict__ Kp, float* __restrict__ dn)
{
    int idx = blockIdx.x * blockDim.x + threadIdx.x;   // 16384
    int t = idx >> 4, h = idx & 15;
    float* p = Kp + (size_t)t * DM + h * DH;
    float x[64], o[64];
    float ss = 0.0f;
    #pragma unroll
    for (int i = 0; i < 16; i++) *(float4*)&x[i*4] = *(const float4*)(p + i*4);
    #pragma unroll
    for (int d = 0; d < 64; d++) ss = fmaf(x[d], x[d], ss);  // norm invariant under rope
    #pragma unroll
    for (int d = 0; d < 32; d++){
        float inv = expf(-(float)d * 0.28782313662425575f);
        float ang = (float)t * inv;
        float s, c; sincosf(ang, &s, &c);
        float x1 = x[2*d], x2 = x[2*d+1];
        o[d]      = x1 * c - x2 * s;
        o[d + 32] = x1 * s + x2 * c;
    }
    #pragma unroll
    for (int i = 0; i < 16; i++) *(float4*)(p + i*4) = *(float4*)&o[i*4];
    dn[h * T_SEQ + t] = sqrtf(fmaxf(ss, 1e-6f));
}

// One block per (q-tile of 64, head). ctx layout: [h][t][d]
__global__ __launch_bounds__(256) void attn_kernel(
    const float* __restrict__ Q, const float* __restrict__ Kp,
    const float* __restrict__ V, const float* __restrict__ dn,
    const float* __restrict__ sinks, const float* __restrict__ vnulls,
    float* __restrict__ ctx)
{
    __shared__ float qst[64][68];   // [d][q] transposed
    __shared__ float kst[64][68];   // [d][s] transposed; reused as ws[q][s]
    __shared__ float vs [64][68];   // [s][d]
    __shared__ float dens[64];

    const int tid = threadIdx.x;
    const int h   = blockIdx.y;
    const int kh  = h & 15;
    const int qt  = blockIdx.x;
    const int t0  = qt << 6;
    const int tx  = (tid >> 2) & 15;                 // s-block (scores) / d-block (PV)
    const int ty  = (tid & 3) | ((tid >> 6) << 2);   // q-block
    const int lr  = tid >> 4;                        // tile-load row base
    const int lc4 = (tid & 15) << 2;                 // tile-load col (x4)

    // stage Q tile (transposed) once
    #pragma unroll
    for (int i = 0; i < 4; i++){
        int r = lr + (i << 4);
        float4 qv = *(const float4*)&Q[(size_t)(t0 + r) * (HTOT*DH) + h*DH + lc4];
        qst[lc4+0][r] = qv.x; qst[lc4+1][r] = qv.y;
        qst[lc4+2][r] = qv.z; qst[lc4+3][r] = qv.w;
    }

    float acc[4][4] = {};
    float den[4]    = {};

    for (int st = 0; st <= qt; ++st){
        int s0 = st << 6;
        #pragma unroll
        for (int i = 0; i < 4; i++){
            int r = lr + (i << 4);
            float4 kv = *(const float4*)&Kp[(size_t)(s0 + r) * DM + kh*DH + lc4];
            kst[lc4+0][r] = kv.x; kst[lc4+1][r] = kv.y;
            kst[lc4+2][r] = kv.z; kst[lc4+3][r] = kv.w;
            float4 vv = *(const float4*)&V[(size_t)(s0 + r) * (HTOT*DH) + h*DH + lc4];
            *(float4*)&vs[r][lc4] = vv;
        }
        if (tid < 64) dens[tid] = dn[kh * T_SEQ + s0 + tid];
        __syncthreads();

        // scores: dot[i][j] = q_{4ty+i} . k_{4tx+j}
        float dot[4][4] = {};
        #pragma unroll 8
        for (int d = 0; d < 64; ++d){
            float qv[4], kv[4];
            *(float4*)qv = *(const float4*)&qst[d][ty << 2];
            *(float4*)kv = *(const float4*)&kst[d][tx << 2];
            #pragma unroll
            for (int i = 0; i < 4; i++)
                #pragma unroll
                for (int j = 0; j < 4; j++)
                    dot[i][j] = fmaf(qv[i], kv[j], dot[i][j]);
        }
        __syncthreads();   // everyone done reading kst before it becomes ws

        const bool diag = (st == qt);
        #pragma unroll
        for (int i = 0; i < 4; i++){
            #pragma unroll
            for (int j = 0; j < 4; j++){
                int s = (tx << 2) + j;
                float w = 0.0f;
                if (!diag || s <= ((ty << 2) + i)){
                    float xx = dot[i][j] * 0.125f / dens[s];
                    w = softplusf(xx);
                    w = w / (1.0f + expf(-SILU_SCALE * w));   // w * sigmoid(SCALE*w)
                }
                kst[(ty << 2) + i][s] = w;    // kst reused as ws[q][s]
            }
        }
        __syncthreads();

        // PV: acc[i][j] += sum_s w[q_i][s] * v[s][d_j]
        for (int s = 0; s < 64; ++s){
            float wv[4];
            #pragma unroll
            for (int i = 0; i < 4; i++) wv[i] = kst[(ty << 2) + i][s];
            float vv[4];
            *(float4*)vv = *(const float4*)&vs[s][tx << 2];
            #pragma unroll
            for (int i = 0; i < 4; i++){
                den[i] += wv[i];
                #pragma unroll
                for (int j = 0; j < 4; j++)
                    acc[i][j] = fmaf(wv[i], vv[j], acc[i][j]);
            }
        }
        __syncthreads();   // before next tile's kst/vs loads
    }

    float sinkv = tanhf(sinks[h]) + 1e-6f;
    #pragma unroll
    for (int i = 0; i < 4; i++){
        int t = t0 + (ty << 2) + i;
        float alpha = 1.0f / (den[i] + sinkv + 1e-6f);
        #pragma unroll
        for (int j = 0; j < 4; j++){
            int d = (tx << 2) + j;
            float o = (acc[i][j] + sinkv * vnulls[h * DH + d]) * alpha;
            ctx[((size_t)h * T_SEQ + t) * DH + d] = o;
        }
    }
}

// avg over 4 branches: avg[t][nh*64+d] = 0.25 * sum_br ctx[br*16+nh][t][d]
__global__ void avg_kernel(const float* __restrict__ ctx, float* __restrict__ avg)
{
    int idx = blockIdx.x * blockDim.x + threadIdx.x;   // 1M
    int t = idx >> 10, c = idx & 1023;
    int nh = c >> 6, d = c & 63;
    float s = 0.0f;
    #pragma unroll
    for (int br = 0; br < 4; br++)
        s += ctx[((size_t)(br * 16 + nh) * T_SEQ + t) * DH + d];
    avg[idx] = 0.25f * s;
}

extern "C" void kernel_launch(void* const* d_in, const int* in_sizes, int n_in,
                              void* d_out, int out_size, void* d_ws, size_t ws_size,
                              hipStream_t stream)
{
    (void)in_sizes; (void)n_in; (void)out_size; (void)ws_size;
    const float* X      = (const float*)d_in[0];
    const float* Wq     = (const float*)d_in[1];
    const float* bq     = (const float*)d_in[2];
    const float* Wk     = (const float*)d_in[3];
    const float* bk     = (const float*)d_in[4];
    const float* Wv     = (const float*)d_in[5];
    const float* bv     = (const float*)d_in[6];
    const float* sinks  = (const float*)d_in[7];
    const float* vnulls = (const float*)d_in[8];
    const float* Wo     = (const float*)d_in[9];
    const float* bo     = (const float*)d_in[10];
    float* out = (float*)d_out;

    float* Qb  = (float*)d_ws;                         // 1024*4096
    float* Kb  = Qb  + (size_t)T_SEQ * 4096;           // 1024*1024
    float* Vb  = Kb  + (size_t)T_SEQ * 1024;           // 1024*4096
    float* ctx = Vb  + (size_t)T_SEQ * 4096;           // 64*1024*64
    float* dnm = ctx + (size_t)HTOT * T_SEQ * DH;      // 16*1024
    float* avg = dnm + (size_t)NH16 * T_SEQ;           // 1024*1024

    dim3 blk(256);
    sgemm_kernel<<<dim3(64, 16), blk, 0, stream>>>(X, Wq, bq, Qb, 1024, 4096, 1024);
    sgemm_kernel<<<dim3(16, 16), blk, 0, stream>>>(X, Wk, bk, Kb, 1024, 1024, 1024);
    sgemm_kernel<<<dim3(64, 16), blk, 0, stream>>>(X, Wv, bv, Vb, 1024, 4096, 1024);
    rope_q_kernel<<<dim3(65536 / 256), blk, 0, stream>>>(Qb);
    rope_k_kernel<<<dim3(16384 / 256), blk, 0, stream>>>(Kb, dnm);
    attn_kernel<<<dim3(16, 64), blk, 0, stream>>>(Qb, Kb, Vb, dnm, sinks, vnulls, ctx);
    avg_kernel<<<dim3(4096), blk, 0, stream>>>(ctx, avg);
    sgemm_kernel<<<dim3(16, 16), blk, 0, stream>>>(avg, Wo, bo, out, 1024, 1024, 1024);
}

// Round 2
// 322.714 us; speedup vs baseline: 3.1843x; 3.1843x over previous
//
#include <hip/hip_runtime.h>
#include <math.h>

#define SILU_SCALE 1.8137993642342178f   // pi/sqrt(3)
#define QKV_N 9216                       // 4096 Q | 1024 K | 4096 V
#define LDP 72                           // LDS row stride (shorts): 144B, 16B-aligned, breaks bank alignment

typedef __attribute__((ext_vector_type(8))) short bf16x8;
typedef __attribute__((ext_vector_type(4))) float f32x4;

__device__ __forceinline__ unsigned short f2bf(float f){
    union { float f; unsigned int i; } u; u.f = f;
    unsigned int r = u.i + 0x7FFFu + ((u.i >> 16) & 1u);   // RNE
    return (unsigned short)(r >> 16);
}
__device__ __forceinline__ float bf2f(unsigned short s){
    union { unsigned int i; float f; } u; u.i = ((unsigned int)s) << 16;
    return u.f;
}

// ---------------- converts ----------------
__global__ void conv_bf16(const float* __restrict__ X, unsigned short* __restrict__ Y)
{
    int i = (blockIdx.x * blockDim.x + threadIdx.x) * 8;
    float4 a = *(const float4*)&X[i];
    float4 b = *(const float4*)&X[i + 4];
    union { unsigned short u[8]; uint4 v; } o;
    o.u[0]=f2bf(a.x); o.u[1]=f2bf(a.y); o.u[2]=f2bf(a.z); o.u[3]=f2bf(a.w);
    o.u[4]=f2bf(b.x); o.u[5]=f2bf(b.y); o.u[6]=f2bf(b.z); o.u[7]=f2bf(b.w);
    *(uint4*)&Y[i] = o.v;
}

// W [K][N] fp32 -> Wt [N][K] bf16, 32x32 LDS tile transpose
__global__ __launch_bounds__(256) void conv_transpose(
    const float* __restrict__ W, unsigned short* __restrict__ Wt, int K, int N)
{
    __shared__ float t[32][33];
    const int k0 = blockIdx.y * 32, n0 = blockIdx.x * 32;
    const int r = threadIdx.x >> 3, c4 = (threadIdx.x & 7) * 4;
    float4 v = *(const float4*)&W[(size_t)(k0 + r) * N + n0 + c4];
    t[c4+0][r] = v.x; t[c4+1][r] = v.y; t[c4+2][r] = v.z; t[c4+3][r] = v.w;
    __syncthreads();
    union { unsigned short u[4]; uint2 v; } o;
    o.u[0]=f2bf(t[r][c4+0]); o.u[1]=f2bf(t[r][c4+1]);
    o.u[2]=f2bf(t[r][c4+2]); o.u[3]=f2bf(t[r][c4+3]);
    *(uint2*)&Wt[(size_t)(n0 + r) * K + k0 + c4] = o.v;
}

__global__ void pack_bias(const float* __restrict__ bq, const float* __restrict__ bk,
                          const float* __restrict__ bv, float* __restrict__ b)
{
    int i = blockIdx.x * blockDim.x + threadIdx.x;   // 9216
    float v;
    if (i < 4096) v = bq[i];
    else if (i < 5120) v = bk[i - 4096];
    else v = bv[i - 5120];
    b[i] = v;
}

// ---------------- bf16 MFMA GEMM: C = A[M,K] @ Bt[N,K]^T + bias ----------------
template<int BM, int BN, int OUTBF>
__global__ __launch_bounds__(256) void gemm_k(
    const unsigned short* __restrict__ A,
    const unsigned short* __restrict__ Bt,
    const float* __restrict__ bias,
    void* __restrict__ Cout, int M, int N, int K)
{
    constexpr int MT = BM / 32;   // 16-row m-tiles per wave
    constexpr int NT = BN / 32;
    __shared__ unsigned short As[BM][LDP];
    __shared__ unsigned short Bs[BN][LDP];
    const int tid  = threadIdx.x;
    const int wave = tid >> 6;
    const int lane = tid & 63;
    const int l15  = lane & 15;
    const int quad = lane >> 4;
    const int m0 = blockIdx.y * BM;
    const int n0 = blockIdx.x * BN;
    const int wm = (wave >> 1) * (BM / 2);
    const int wn = (wave & 1) * (BN / 2);
    const int srow = tid >> 3;   // 0..31
    const int sch  = tid & 7;    // 16B chunk along K

    f32x4 acc[MT][NT];
    #pragma unroll
    for (int i = 0; i < MT; i++)
        #pragma unroll
        for (int j = 0; j < NT; j++)
            acc[i][j] = (f32x4){0.f, 0.f, 0.f, 0.f};

    for (int k0 = 0; k0 < K; k0 += 64){
        #pragma unroll
        for (int i = 0; i < BM / 32; i++){
            int r = srow + i * 32;
            *(uint4*)&As[r][sch * 8] = *(const uint4*)&A[(size_t)(m0 + r) * K + k0 + sch * 8];
        }
        #pragma unroll
        for (int i = 0; i < BN / 32; i++){
            int r = srow + i * 32;
            *(uint4*)&Bs[r][sch * 8] = *(const uint4*)&Bt[(size_t)(n0 + r) * K + k0 + sch * 8];
        }
        __syncthreads();
        #pragma unroll
        for (int ks = 0; ks < 2; ks++){
            bf16x8 af[MT], bfr[NT];
            #pragma unroll
            for (int i = 0; i < MT; i++)
                af[i] = *(const bf16x8*)&As[wm + i * 16 + l15][ks * 32 + quad * 8];
            #pragma unroll
            for (int j = 0; j < NT; j++)
                bfr[j] = *(const bf16x8*)&Bs[wn + j * 16 + l15][ks * 32 + quad * 8];
            #pragma unroll
            for (int i = 0; i < MT; i++)
                #pragma unroll
                for (int j = 0; j < NT; j++)
                    acc[i][j] = __builtin_amdgcn_mfma_f32_16x16x32_bf16(af[i], bfr[j], acc[i][j], 0, 0, 0);
        }
        __syncthreads();
    }
    #pragma unroll
    for (int i = 0; i < MT; i++){
        #pragma unroll
        for (int j = 0; j < NT; j++){
            int col = n0 + wn + j * 16 + l15;
            float bv = bias[col];
            #pragma unroll
            for (int r = 0; r < 4; r++){
                int row = m0 + wm + i * 16 + quad * 4 + r;
                float v = acc[i][j][r] + bv;
                if (OUTBF) ((unsigned short*)Cout)[(size_t)row * N + col] = f2bf(v);
                else       ((float*)Cout)[(size_t)row * N + col] = v;
            }
        }
    }
}

// ---------------- RoPE ----------------
__global__ void rope_q_kernel(unsigned short* __restrict__ qkv)
{
    int idx = blockIdx.x * blockDim.x + threadIdx.x;   // 65536: (t, h 0..63)
    int t = idx >> 6, h = idx & 63;
    unsigned short* p = qkv + (size_t)t * QKV_N + h * 64;
    uint4 raw[8];
    #pragma unroll
    for (int i = 0; i < 8; i++) raw[i] = *(const uint4*)(p + i * 8);
    const unsigned short* rp = (const unsigned short*)raw;
    float x[64];
    #pragma unroll
    for (int i = 0; i < 64; i++) x[i] = bf2f(rp[i]);
    unsigned short o[64];
    #pragma unroll
    for (int d = 0; d < 32; d++){
        float inv = expf(-(float)d * 0.28782313662425575f);   // ln(1e4)/32
        float s, c; sincosf((float)t * inv, &s, &c);
        float x1 = x[2*d], x2 = x[2*d+1];
        o[d]      = f2bf(x1 * c - x2 * s);
        o[d + 32] = f2bf(x1 * s + x2 * c);
    }
    #pragma unroll
    for (int i = 0; i < 8; i++) *(uint4*)(p + i * 8) = ((const uint4*)o)[i];
}

__global__ void rope_k_kernel(unsigned short* __restrict__ qkv, float* __restrict__ dn)
{
    int idx = blockIdx.x * blockDim.x + threadIdx.x;   // 16384: (t, kh 0..15)
    int t = idx >> 4, h = idx & 15;
    unsigned short* p = qkv + (size_t)t * QKV_N + 4096 + h * 64;
    uint4 raw[8];
    #pragma unroll
    for (int i = 0; i < 8; i++) raw[i] = *(const uint4*)(p + i * 8);
    const unsigned short* rp = (const unsigned short*)raw;
    float x[64];
    #pragma unroll
    for (int i = 0; i < 64; i++) x[i] = bf2f(rp[i]);
    unsigned short o[64];
    float ss = 0.f;
    #pragma unroll
    for (int d = 0; d < 32; d++){
        float inv = expf(-(float)d * 0.28782313662425575f);
        float s, c; sincosf((float)t * inv, &s, &c);
        float x1 = x[2*d], x2 = x[2*d+1];
        float a = x1 * c - x2 * s;
        float b = x1 * s + x2 * c;
        ss = fmaf(a, a, fmaf(b, b, ss));
        o[d]      = f2bf(a);
        o[d + 32] = f2bf(b);
    }
    #pragma unroll
    for (int i = 0; i < 8; i++) *(uint4*)(p + i * 8) = ((const uint4*)o)[i];
    dn[h * 1024 + t] = sqrtf(fmaxf(ss, 1e-6f));
}

// ---------------- fused attention (MFMA) ----------------
// grid (qt 0..15, h 0..63); block 256 = 4 waves, wave w owns q rows [w*16, w*16+16)
__global__ __launch_bounds__(256) void attn_mfma(
    const unsigned short* __restrict__ qkv,
    const float* __restrict__ dn,
    const float* __restrict__ sinks, const float* __restrict__ vnulls,
    unsigned short* __restrict__ ctx)       // [64][1024][64] bf16
{
    __shared__ unsigned short ks[64][LDP];  // K tile [s][d]
    __shared__ unsigned short vt[64][LDP];  // V tile transposed [d][s]
    __shared__ unsigned short ws[64][LDP];  // P tile [q][s]  (wave-private rows)
    __shared__ float dl[64];

    const int tid  = threadIdx.x;
    const int wave = tid >> 6;
    const int lane = tid & 63;
    const int l15  = lane & 15;
    const int quad = lane >> 4;
    const int h  = blockIdx.y;
    const int kh = h & 15;
    const int qt = blockIdx.x;
    const int t0 = qt << 6;

    const unsigned short* Q = qkv;                 // col offset h*64
    const unsigned short* K = qkv + 4096;          // col offset kh*64
    const unsigned short* V = qkv + 5120;          // col offset h*64

    // Q fragments straight from global (A-operand: m=l15 within wave's 16 rows)
    bf16x8 qf[2];
    {
        const unsigned short* qp = Q + (size_t)(t0 + wave * 16 + l15) * QKV_N + h * 64;
        qf[0] = *(const bf16x8*)(qp + quad * 8);
        qf[1] = *(const bf16x8*)(qp + 32 + quad * 8);
    }

    // staging indices
    const int srow = tid >> 3;      // 0..31 (coalesced K staging)
    const int sch  = tid & 7;
    const int vrow = tid & 31;      // 0..31 (V transpose staging: lanes walk rows)
    const int vch  = tid >> 5;      // 0..7

    f32x4 acc_o[4];
    #pragma unroll
    for (int i = 0; i < 4; i++) acc_o[i] = (f32x4){0.f, 0.f, 0.f, 0.f};
    float den[4] = {0.f, 0.f, 0.f, 0.f};

    for (int st = 0; st <= qt; st++){
        const int s0 = st << 6;
        __syncthreads();   // previous iteration's PV reads done
        #pragma unroll
        for (int i = 0; i < 2; i++){
            int r = srow + i * 32;
            *(uint4*)&ks[r][sch * 8] =
                *(const uint4*)&K[(size_t)(s0 + r) * QKV_N + kh * 64 + sch * 8];
        }
        #pragma unroll
        for (int i = 0; i < 2; i++){
            int r = vrow + i * 32;
            uint4 vv = *(const uint4*)&V[(size_t)(s0 + r) * QKV_N + h * 64 + vch * 8];
            const unsigned short* pv = (const unsigned short*)&vv;
            #pragma unroll
            for (int j = 0; j < 8; j++) vt[vch * 8 + j][r] = pv[j];
        }
        if (tid < 64) dl[tid] = dn[kh * 1024 + s0 + tid];
        __syncthreads();

        // QK^T + elementwise -> ws (wave-private rows, no barrier needed before PV)
        #pragma unroll
        for (int nt = 0; nt < 4; nt++){
            f32x4 sc = (f32x4){0.f, 0.f, 0.f, 0.f};
            bf16x8 kf0 = *(const bf16x8*)&ks[nt * 16 + l15][quad * 8];
            bf16x8 kf1 = *(const bf16x8*)&ks[nt * 16 + l15][32 + quad * 8];
            sc = __builtin_amdgcn_mfma_f32_16x16x32_bf16(qf[0], kf0, sc, 0, 0, 0);
            sc = __builtin_amdgcn_mfma_f32_16x16x32_bf16(qf[1], kf1, sc, 0, 0, 0);
            const int s_loc  = nt * 16 + l15;
            const int s_glob = s0 + s_loc;
            const float dinv = __fdividef(0.125f, dl[s_loc]);
            const int q_base = wave * 16 + quad * 4;
            const int q_glob = t0 + q_base;
            #pragma unroll
            for (int r = 0; r < 4; r++){
                float w = 0.f;
                if (s_glob <= q_glob + r){
                    float xx = sc[r] * dinv;
                    float e  = __expf(-fabsf(xx));
                    float sp = fmaxf(xx, 0.f) + __logf(1.f + e);
                    w = __fdividef(sp, 1.f + __expf(-SILU_SCALE * sp));
                }
                den[r] += w;
                ws[q_base + r][s_loc] = f2bf(w);
            }
        }

        // PV
        bf16x8 pf0 = *(const bf16x8*)&ws[wave * 16 + l15][quad * 8];
        bf16x8 pf1 = *(const bf16x8*)&ws[wave * 16 + l15][32 + quad * 8];
        #pragma unroll
        for (int dt = 0; dt < 4; dt++){
            bf16x8 vf0 = *(const bf16x8*)&vt[dt * 16 + l15][quad * 8];
            bf16x8 vf1 = *(const bf16x8*)&vt[dt * 16 + l15][32 + quad * 8];
            acc_o[dt] = __builtin_amdgcn_mfma_f32_16x16x32_bf16(pf0, vf0, acc_o[dt], 0, 0, 0);
            acc_o[dt] = __builtin_amdgcn_mfma_f32_16x16x32_bf16(pf1, vf1, acc_o[dt], 0, 0, 0);
        }
    }

    // row-sum reduction across the 16 lanes of each quad
    #pragma unroll
    for (int r = 0; r < 4; r++){
        float d = den[r];
        d += __shfl_xor(d, 1); d += __shfl_xor(d, 2);
        d += __shfl_xor(d, 4); d += __shfl_xor(d, 8);
        den[r] = d;
    }
    float sinkv = tanhf(sinks[h]) + 1e-6f;
    #pragma unroll
    for (int r = 0; r < 4; r++){
        int q_glob = t0 + wave * 16 + quad * 4 + r;
        float alpha = __fdividef(1.f, den[r] + sinkv + 1e-6f);
        #pragma unroll
        for (int dt = 0; dt < 4; dt++){
            int d = dt * 16 + l15;
            float o = (acc_o[dt][r] + sinkv * vnulls[h * 64 + d]) * alpha;
            ctx[((size_t)h * 1024 + q_glob) * 64 + d] = f2bf(o);
        }
    }
}

// avg over 4 branches -> bf16 [t][nh*64+d]
__global__ void avg_kernel(const unsigned short* __restrict__ ctx, unsigned short* __restrict__ avg)
{
    int idx = blockIdx.x * blockDim.x + threadIdx.x;   // 1M
    int t = idx >> 10, c = idx & 1023;
    int nh = c >> 6, d = c & 63;
    float s = 0.f;
    #pragma unroll
    for (int br = 0; br < 4; br++)
        s += bf2f(ctx[((size_t)(br * 16 + nh) * 1024 + t) * 64 + d]);
    avg[idx] = f2bf(0.25f * s);
}

extern "C" void kernel_launch(void* const* d_in, const int* in_sizes, int n_in,
                              void* d_out, int out_size, void* d_ws, size_t ws_size,
                              hipStream_t stream)
{
    (void)in_sizes; (void)n_in; (void)out_size; (void)ws_size;
    const float* X      = (const float*)d_in[0];
    const float* Wq     = (const float*)d_in[1];
    const float* bq     = (const float*)d_in[2];
    const float* Wk     = (const float*)d_in[3];
    const float* bk     = (const float*)d_in[4];
    const float* Wv     = (const float*)d_in[5];
    const float* bv     = (const float*)d_in[6];
    const float* sinks  = (const float*)d_in[7];
    const float* vnulls = (const float*)d_in[8];
    const float* Wo     = (const float*)d_in[9];
    const float* bo     = (const float*)d_in[10];
    float* out = (float*)d_out;

    unsigned short* w16   = (unsigned short*)d_ws;
    unsigned short* Xb    = w16;                                  // 1M
    unsigned short* WqkvT = Xb    + (size_t)1024 * 1024;          // 9216*1024
    unsigned short* QKVb  = WqkvT + (size_t)QKV_N * 1024;         // 1024*9216
    unsigned short* WoT   = QKVb  + (size_t)1024 * QKV_N;         // 1M
    unsigned short* ctxb  = WoT   + (size_t)1024 * 1024;          // 4M
    unsigned short* avgb  = ctxb  + (size_t)64 * 1024 * 64;       // 1M
    float* qkvb = (float*)(avgb + (size_t)1024 * 1024);           // 9216
    float* dnf  = qkvb + QKV_N;                                   // 16*1024

    dim3 blk(256);
    conv_bf16<<<512, blk, 0, stream>>>(X, Xb);
    conv_transpose<<<dim3(128, 32), blk, 0, stream>>>(Wq, WqkvT,                       1024, 4096);
    conv_transpose<<<dim3(32, 32),  blk, 0, stream>>>(Wk, WqkvT + (size_t)4096 * 1024, 1024, 1024);
    conv_transpose<<<dim3(128, 32), blk, 0, stream>>>(Wv, WqkvT + (size_t)5120 * 1024, 1024, 4096);
    conv_transpose<<<dim3(32, 32),  blk, 0, stream>>>(Wo, WoT,                         1024, 1024);
    pack_bias<<<36, blk, 0, stream>>>(bq, bk, bv, qkvb);

    gemm_k<128, 128, 1><<<dim3(72, 8), blk, 0, stream>>>(Xb, WqkvT, qkvb, QKVb, 1024, QKV_N, 1024);
    rope_q_kernel<<<256, blk, 0, stream>>>(QKVb);
    rope_k_kernel<<<64, blk, 0, stream>>>(QKVb, dnf);
    attn_mfma<<<dim3(16, 64), blk, 0, stream>>>(QKVb, dnf, sinks, vnulls, ctxb);
    avg_kernel<<<4096, blk, 0, stream>>>(ctxb, avgb);
    gemm_k<64, 64, 0><<<dim3(16, 16), blk, 0, stream>>>(avgb, WoT, bo, out, 1024, 1024, 1024);
}

// Round 3
// 237.565 us; speedup vs baseline: 4.3256x; 1.3584x over previous
//
#include <hip/hip_runtime.h>
#include <math.h>

#define SILU_SCALE 1.8137993642342178f   // pi/sqrt(3)
#define QKV_N 9216                       // 4096 Q | 1024 K | 4096 V

typedef __attribute__((ext_vector_type(8))) short bf16x8;
typedef __attribute__((ext_vector_type(4))) float f32x4;

__device__ __forceinline__ unsigned short f2bf(float f){
    union { float f; unsigned int i; } u; u.f = f;
    unsigned int r = u.i + 0x7FFFu + ((u.i >> 16) & 1u);   // RNE
    return (unsigned short)(r >> 16);
}
__device__ __forceinline__ float bf2f(unsigned short s){
    union { unsigned int i; float f; } u; u.i = ((unsigned int)s) << 16;
    return u.f;
}

// async global->LDS, 16B per lane; LDS dest = wave-uniform base + lane*16
__device__ __forceinline__ void gload_lds16(const void* g, void* l){
    __builtin_amdgcn_global_load_lds(
        (const __attribute__((address_space(1))) void*)g,
        (__attribute__((address_space(3))) void*)l, 16, 0, 0);
}

// ---------------- fused prep: 4 weight transposes + X convert + bias pack ----------------
// blocks: [0,4096) Wq | [4096,5120) Wk | [5120,9216) Wv | [9216,10240) Wo |
//         [10240,10752) X conv | [10752,10788) bias
__global__ __launch_bounds__(256) void prep_kernel(
    const float* __restrict__ X,
    const float* __restrict__ Wq, const float* __restrict__ Wk,
    const float* __restrict__ Wv, const float* __restrict__ Wo,
    const float* __restrict__ bq, const float* __restrict__ bk,
    const float* __restrict__ bv,
    unsigned short* __restrict__ Xb, unsigned short* __restrict__ WqkvT,
    unsigned short* __restrict__ WoT, float* __restrict__ qkvb)
{
    __shared__ float t[32][33];
    int b = blockIdx.x;
    const int tid = threadIdx.x;

    if (b >= 10240){
        if (b < 10752){   // X fp32 -> bf16, 8/thread
            int i = ((b - 10240) * 256 + tid) * 8;
            float4 a = *(const float4*)&X[i];
            float4 c = *(const float4*)&X[i + 4];
            union { unsigned short u[8]; uint4 v; } o;
            o.u[0]=f2bf(a.x); o.u[1]=f2bf(a.y); o.u[2]=f2bf(a.z); o.u[3]=f2bf(a.w);
            o.u[4]=f2bf(c.x); o.u[5]=f2bf(c.y); o.u[6]=f2bf(c.z); o.u[7]=f2bf(c.w);
            *(uint4*)&Xb[i] = o.v;
        } else {          // bias pack
            int i = (b - 10752) * 256 + tid;
            float v;
            if (i < 4096) v = bq[i];
            else if (i < 5120) v = bk[i - 4096];
            else v = bv[i - 5120];
            qkvb[i] = v;
        }
        return;
    }

    const float* W; unsigned short* Wt; int N, tiles_x;
    if (b < 4096)      { W = Wq; Wt = WqkvT;                       N = 4096; tiles_x = 128; }
    else if (b < 5120) { b -= 4096; W = Wk; Wt = WqkvT + (size_t)4096*1024; N = 1024; tiles_x = 32; }
    else if (b < 9216) { b -= 5120; W = Wv; Wt = WqkvT + (size_t)5120*1024; N = 4096; tiles_x = 128; }
    else               { b -= 9216; W = Wo; Wt = WoT;              N = 1024; tiles_x = 32; }

    const int k0 = (b / tiles_x) * 32, n0 = (b % tiles_x) * 32;
    const int r = tid >> 3, c4 = (tid & 7) * 4;
    float4 v = *(const float4*)&W[(size_t)(k0 + r) * N + n0 + c4];
    t[c4+0][r] = v.x; t[c4+1][r] = v.y; t[c4+2][r] = v.z; t[c4+3][r] = v.w;
    __syncthreads();
    union { unsigned short u[4]; uint2 v; } o;
    o.u[0]=f2bf(t[r][c4+0]); o.u[1]=f2bf(t[r][c4+1]);
    o.u[2]=f2bf(t[r][c4+2]); o.u[3]=f2bf(t[r][c4+3]);
    *(uint2*)&Wt[(size_t)(n0 + r) * 1024 + k0 + c4] = o.v;
}

// ---------------- bf16 MFMA GEMM (m97-style): C = A[M,K] @ Bt[N,K]^T + bias ----------------
// LDS unpadded, XOR-swizzled: slot(row, phys) holds logical chunk phys^(row&7);
// swizzle applied on the GLOBAL address so global_load_lds lane-contiguity holds.
template<int BM, int BN, int OUTBF>
__global__ __launch_bounds__(256) void gemm_k(
    const unsigned short* __restrict__ A,
    const unsigned short* __restrict__ Bt,
    const float* __restrict__ bias,
    void* __restrict__ Cout, int M, int N, int K)
{
    constexpr int MT = BM / 32;
    constexpr int NT = BN / 32;
    __shared__ unsigned short As[BM * 64];
    __shared__ unsigned short Bs[BN * 64];
    const int tid  = threadIdx.x;
    const int wave = tid >> 6;
    const int lane = tid & 63;
    const int l15  = lane & 15;
    const int quad = lane >> 4;
    const int m0 = blockIdx.y * BM;
    const int n0 = blockIdx.x * BN;
    const int wm = (wave >> 1) * (BM / 2);
    const int wn = (wave & 1) * (BN / 2);

    f32x4 acc[MT][NT];
    #pragma unroll
    for (int i = 0; i < MT; i++)
        #pragma unroll
        for (int j = 0; j < NT; j++)
            acc[i][j] = (f32x4){0.f, 0.f, 0.f, 0.f};

    for (int k0 = 0; k0 < K; k0 += 64){
        #pragma unroll
        for (int j = 0; j < (BM * 8) / 256; j++){
            int bslot = j * 256 + wave * 64;
            int slot = bslot + lane;
            int row = slot >> 3, phys = slot & 7;
            int c = phys ^ (row & 7);
            gload_lds16(&A[(size_t)(m0 + row) * K + k0 + c * 8], &As[bslot * 8]);
        }
        #pragma unroll
        for (int j = 0; j < (BN * 8) / 256; j++){
            int bslot = j * 256 + wave * 64;
            int slot = bslot + lane;
            int row = slot >> 3, phys = slot & 7;
            int c = phys ^ (row & 7);
            gload_lds16(&Bt[(size_t)(n0 + row) * K + k0 + c * 8], &Bs[bslot * 8]);
        }
        __syncthreads();
        #pragma unroll
        for (int ks = 0; ks < 2; ks++){
            bf16x8 af[MT], bfr[NT];
            #pragma unroll
            for (int i = 0; i < MT; i++){
                int row = wm + i * 16 + l15;
                int phys = (ks * 4 + quad) ^ (row & 7);
                af[i] = *(const bf16x8*)&As[row * 64 + phys * 8];
            }
            #pragma unroll
            for (int j = 0; j < NT; j++){
                int row = wn + j * 16 + l15;
                int phys = (ks * 4 + quad) ^ (row & 7);
                bfr[j] = *(const bf16x8*)&Bs[row * 64 + phys * 8];
            }
            #pragma unroll
            for (int i = 0; i < MT; i++)
                #pragma unroll
                for (int j = 0; j < NT; j++)
                    acc[i][j] = __builtin_amdgcn_mfma_f32_16x16x32_bf16(af[i], bfr[j], acc[i][j], 0, 0, 0);
        }
        __syncthreads();
    }
    #pragma unroll
    for (int i = 0; i < MT; i++){
        #pragma unroll
        for (int j = 0; j < NT; j++){
            int col = n0 + wn + j * 16 + l15;
            float bv = bias[col];
            #pragma unroll
            for (int r = 0; r < 4; r++){
                int row = m0 + wm + i * 16 + quad * 4 + r;
                float v = acc[i][j][r] + bv;
                if (OUTBF) ((unsigned short*)Cout)[(size_t)row * N + col] = f2bf(v);
                else       ((float*)Cout)[(size_t)row * N + col] = v;
            }
        }
    }
}

// ---------------- RoPE (Q + K fused) ----------------
__global__ void rope_kernel(unsigned short* __restrict__ qkv, float* __restrict__ dninv)
{
    int idx = blockIdx.x * blockDim.x + threadIdx.x;   // 81920
    if (idx < 65536){   // Q: (t, h 0..63)
        int t = idx >> 6, h = idx & 63;
        unsigned short* p = qkv + (size_t)t * QKV_N + h * 64;
        uint4 raw[8];
        #pragma unroll
        for (int i = 0; i < 8; i++) raw[i] = *(const uint4*)(p + i * 8);
        const unsigned short* rp = (const unsigned short*)raw;
        float x[64];
        #pragma unroll
        for (int i = 0; i < 64; i++) x[i] = bf2f(rp[i]);
        unsigned short o[64];
        #pragma unroll
        for (int d = 0; d < 32; d++){
            float inv = expf(-(float)d * 0.28782313662425575f);   // ln(1e4)/32
            float s, c; sincosf((float)t * inv, &s, &c);
            float x1 = x[2*d], x2 = x[2*d+1];
            o[d]      = f2bf(x1 * c - x2 * s);
            o[d + 32] = f2bf(x1 * s + x2 * c);
        }
        #pragma unroll
        for (int i = 0; i < 8; i++) *(uint4*)(p + i * 8) = ((const uint4*)o)[i];
    } else {            // K: (t, kh 0..15) + 0.125/||k||
        idx -= 65536;
        int t = idx >> 4, h = idx & 15;
        unsigned short* p = qkv + (size_t)t * QKV_N + 4096 + h * 64;
        uint4 raw[8];
        #pragma unroll
        for (int i = 0; i < 8; i++) raw[i] = *(const uint4*)(p + i * 8);
        const unsigned short* rp = (const unsigned short*)raw;
        float x[64];
        #pragma unroll
        for (int i = 0; i < 64; i++) x[i] = bf2f(rp[i]);
        unsigned short o[64];
        float ss = 0.f;
        #pragma unroll
        for (int d = 0; d < 32; d++){
            float inv = expf(-(float)d * 0.28782313662425575f);
            float s, c; sincosf((float)t * inv, &s, &c);
            float x1 = x[2*d], x2 = x[2*d+1];
            float a = x1 * c - x2 * s;
            float b = x1 * s + x2 * c;
            ss = fmaf(a, a, fmaf(b, b, ss));
            o[d]      = f2bf(a);
            o[d + 32] = f2bf(b);
        }
        #pragma unroll
        for (int i = 0; i < 8; i++) *(uint4*)(p + i * 8) = ((const uint4*)o)[i];
        dninv[h * 1024 + t] = 0.125f / sqrtf(fmaxf(ss, 1e-6f));
    }
}

// ---------------- fused attention ----------------
// grid (pi 0..7, h 0..63); 512 thr = 8 waves. Waves 0-3: qt=pi rows; waves 4-7: qt=15-pi.
// Complementary pairing -> exactly 17 compute-iters per SIMD; K/V/dn staged once per pair.
__global__ __launch_bounds__(512) void attn_mfma(
    const unsigned short* __restrict__ qkv,
    const float* __restrict__ dninv,
    const float* __restrict__ sinks, const float* __restrict__ vnulls,
    unsigned short* __restrict__ ctx)       // [64][1024][64] bf16
{
    __shared__ unsigned short ks[64 * 64];          // [s][chunk ^ (s&7)]           8KB
    __shared__ unsigned short vt[64 * 64];          // [d][chunk ^ ((d^(d>>3))&7)]  8KB
    __shared__ unsigned short ws[2][64][72];        // P [tile][q][s], +pad         18KB
    __shared__ float dl[64];

    const int tid  = threadIdx.x;
    const int wave = tid >> 6;          // 0..7
    const int tile = wave >> 2;         // 0=A, 1=B
    const int w    = wave & 3;          // row-block in tile
    const int lane = tid & 63;
    const int l15  = lane & 15;
    const int quad = lane >> 4;
    const int h  = blockIdx.y;
    const int kh = h & 15;
    const int pi = blockIdx.x;
    const int qtB = 15 - pi;
    const int qt  = tile ? qtB : pi;
    const int t0  = qt << 6;

    const unsigned short* Q  = qkv;
    const unsigned short* Kp = qkv + 4096;
    const unsigned short* V  = qkv + 5120;

    bf16x8 qf0, qf1;
    {
        const unsigned short* qp = Q + (size_t)(t0 + w * 16 + l15) * QKV_N + h * 64;
        qf0 = *(const bf16x8*)(qp + quad * 8);
        qf1 = *(const bf16x8*)(qp + 32 + quad * 8);
    }

    f32x4 acc_o[4];
    #pragma unroll
    for (int i = 0; i < 4; i++) acc_o[i] = (f32x4){0.f, 0.f, 0.f, 0.f};
    float den[4] = {0.f, 0.f, 0.f, 0.f};

    const int pr  = (tid & 255) >> 3;   // V staging: s-row pair (threads 0..255)
    const int cch = tid & 7;            // V staging: d-chunk

    for (int st = 0; st <= qtB; st++){
        const int s0 = st << 6;
        __syncthreads();                // previous iteration's LDS reads done

        // K tile: one async global_load_lds per wave (8 waves cover 64 rows x 8 chunks)
        {
            int bslot = wave * 64;
            int slot = bslot + lane;
            int row = slot >> 3, phys = slot & 7;
            int c = phys ^ (row & 7);
            gload_lds16(&Kp[(size_t)(s0 + row) * QKV_N + kh * 64 + c * 8], &ks[bslot * 8]);
        }
        // V tile transposed: threads 0..255, packed s-pair b32 writes, conflict-free swizzle
        if (tid < 256){
            uint4 g0 = *(const uint4*)&V[(size_t)(s0 + 2 * pr)     * QKV_N + h * 64 + cch * 8];
            uint4 g1 = *(const uint4*)&V[(size_t)(s0 + 2 * pr + 1) * QKV_N + h * 64 + cch * 8];
            const unsigned short* p0 = (const unsigned short*)&g0;
            const unsigned short* p1 = (const unsigned short*)&g1;
            #pragma unroll
            for (int j = 0; j < 8; j++){
                int d = cch * 8 + j;
                int physc = (pr >> 2) ^ ((d ^ (d >> 3)) & 7);
                unsigned int val = (unsigned int)p0[j] | ((unsigned int)p1[j] << 16);
                ((unsigned int*)vt)[d * 32 + physc * 4 + (pr & 3)] = val;
            }
        } else if (tid < 320){
            dl[tid - 256] = dninv[kh * 1024 + s0 + (tid - 256)];
        }
        __syncthreads();                // staging visible (drains vmcnt incl. global_load_lds)

        if (st > qt) continue;          // tile-A waves keep staging for tile B
        const bool diag = (st == qt);

        // QK^T + softplus/silu/mask -> ws (wave-private rows)
        #pragma unroll
        for (int nt = 0; nt < 4; nt++){
            const int s_loc  = nt * 16 + l15;
            const int q_base = w * 16 + quad * 4;
            if (diag && nt > w){        // fully-masked sub-tile
                #pragma unroll
                for (int r = 0; r < 4; r++) ws[tile][q_base + r][s_loc] = 0;
                continue;
            }
            f32x4 sc = (f32x4){0.f, 0.f, 0.f, 0.f};
            {
                int srow = nt * 16 + l15;
                int ph0 = quad ^ (srow & 7);
                int ph1 = (4 + quad) ^ (srow & 7);
                bf16x8 kf0 = *(const bf16x8*)&ks[srow * 64 + ph0 * 8];
                bf16x8 kf1 = *(const bf16x8*)&ks[srow * 64 + ph1 * 8];
                sc = __builtin_amdgcn_mfma_f32_16x16x32_bf16(qf0, kf0, sc, 0, 0, 0);
                sc = __builtin_amdgcn_mfma_f32_16x16x32_bf16(qf1, kf1, sc, 0, 0, 0);
            }
            const float dinv  = dl[s_loc];
            const int s_glob  = s0 + s_loc;
            const int q_glob  = t0 + q_base;
            #pragma unroll
            for (int r = 0; r < 4; r++){
                float wv = 0.f;
                if (s_glob <= q_glob + r){
                    float xx = sc[r] * dinv;
                    float e  = __expf(-fabsf(xx));
                    float sp = fmaxf(xx, 0.f) + __logf(1.f + e);
                    wv = __fdividef(sp, 1.f + __expf(-SILU_SCALE * sp));
                }
                den[r] += wv;
                ws[tile][q_base + r][s_loc] = f2bf(wv);
            }
        }

        // PV
        {
            const int prow = w * 16 + l15;
            bf16x8 pf0 = *(const bf16x8*)&ws[tile][prow][quad * 8];
            bf16x8 pf1 = *(const bf16x8*)&ws[tile][prow][32 + quad * 8];
            const bool skip_hi = diag && (w <= 1);   // s>=32 all masked
            #pragma unroll
            for (int dt = 0; dt < 4; dt++){
                int d = dt * 16 + l15;
                int swz = (d ^ (d >> 3)) & 7;
                bf16x8 vf0 = *(const bf16x8*)&vt[d * 64 + (quad ^ swz) * 8];
                acc_o[dt] = __builtin_amdgcn_mfma_f32_16x16x32_bf16(pf0, vf0, acc_o[dt], 0, 0, 0);
                if (!skip_hi){
                    bf16x8 vf1 = *(const bf16x8*)&vt[d * 64 + ((4 + quad) ^ swz) * 8];
                    acc_o[dt] = __builtin_amdgcn_mfma_f32_16x16x32_bf16(pf1, vf1, acc_o[dt], 0, 0, 0);
                }
            }
        }
    }

    // reduce denominator over the 16 lanes of each quad-row
    #pragma unroll
    for (int r = 0; r < 4; r++){
        float d = den[r];
        d += __shfl_xor(d, 1); d += __shfl_xor(d, 2);
        d += __shfl_xor(d, 4); d += __shfl_xor(d, 8);
        den[r] = d;
    }
    float sinkv = tanhf(sinks[h]) + 1e-6f;
    #pragma unroll
    for (int r = 0; r < 4; r++){
        int q_glob = t0 + w * 16 + quad * 4 + r;
        float alpha = __fdividef(1.f, den[r] + sinkv + 1e-6f);
        #pragma unroll
        for (int dt = 0; dt < 4; dt++){
            int d = dt * 16 + l15;
            float o = (acc_o[dt][r] + sinkv * vnulls[h * 64 + d]) * alpha;
            ctx[((size_t)h * 1024 + q_glob) * 64 + d] = f2bf(o);
        }
    }
}

// avg over 4 branches -> bf16 [t][nh*64+d], 8 elems/thread
__global__ void avg_kernel(const unsigned short* __restrict__ ctx, unsigned short* __restrict__ avg)
{
    int i8 = (blockIdx.x * 256 + threadIdx.x) * 8;   // 1M elements
    int t = i8 >> 10, c = i8 & 1023;
    int nh = c >> 6, d = c & 63;
    float s[8] = {};
    #pragma unroll
    for (int br = 0; br < 4; br++){
        uint4 v = *(const uint4*)&ctx[((size_t)(br * 16 + nh) * 1024 + t) * 64 + d];
        const unsigned short* p = (const unsigned short*)&v;
        #pragma unroll
        for (int j = 0; j < 8; j++) s[j] += bf2f(p[j]);
    }
    union { unsigned short u[8]; uint4 v; } o;
    #pragma unroll
    for (int j = 0; j < 8; j++) o.u[j] = f2bf(0.25f * s[j]);
    *(uint4*)&avg[i8] = o.v;
}

extern "C" void kernel_launch(void* const* d_in, const int* in_sizes, int n_in,
                              void* d_out, int out_size, void* d_ws, size_t ws_size,
                              hipStream_t stream)
{
    (void)in_sizes; (void)n_in; (void)out_size; (void)ws_size;
    const float* X      = (const float*)d_in[0];
    const float* Wq     = (const float*)d_in[1];
    const float* bq     = (const float*)d_in[2];
    const float* Wk     = (const float*)d_in[3];
    const float* bk     = (const float*)d_in[4];
    const float* Wv     = (const float*)d_in[5];
    const float* bv     = (const float*)d_in[6];
    const float* sinks  = (const float*)d_in[7];
    const float* vnulls = (const float*)d_in[8];
    const float* Wo     = (const float*)d_in[9];
    const float* bo     = (const float*)d_in[10];
    float* out = (float*)d_out;

    unsigned short* w16   = (unsigned short*)d_ws;
    unsigned short* Xb    = w16;                                  // 1M
    unsigned short* WqkvT = Xb    + (size_t)1024 * 1024;          // 9216*1024
    unsigned short* QKVb  = WqkvT + (size_t)QKV_N * 1024;         // 1024*9216
    unsigned short* WoT   = QKVb  + (size_t)1024 * QKV_N;         // 1M
    unsigned short* ctxb  = WoT   + (size_t)1024 * 1024;          // 4M
    unsigned short* avgb  = ctxb  + (size_t)64 * 1024 * 64;       // 1M
    float* qkvb = (float*)(avgb + (size_t)1024 * 1024);           // 9216
    float* dnf  = qkvb + QKV_N;                                   // 16*1024

    dim3 blk(256);
    prep_kernel<<<10788, blk, 0, stream>>>(X, Wq, Wk, Wv, Wo, bq, bk, bv,
                                           Xb, WqkvT, WoT, qkvb);
    gemm_k<128, 128, 1><<<dim3(72, 8), blk, 0, stream>>>(Xb, WqkvT, qkvb, QKVb, 1024, QKV_N, 1024);
    rope_kernel<<<320, blk, 0, stream>>>(QKVb, dnf);
    attn_mfma<<<dim3(8, 64), dim3(512), 0, stream>>>(QKVb, dnf, sinks, vnulls, ctxb);
    avg_kernel<<<512, blk, 0, stream>>>(ctxb, avgb);
    gemm_k<64, 64, 0><<<dim3(16, 16), blk, 0, stream>>>(avgb, WoT, bo, out, 1024, 1024, 1024);
}

// Round 4
// 212.887 us; speedup vs baseline: 4.8271x; 1.1159x over previous
//
#include <hip/hip_runtime.h>
#include <math.h>

#define SILU_SCALE 1.8137993642342178f   // pi/sqrt(3)
#define QKV_N 9216                       // 4096 Q | 1024 K | 4096 V
#define LN2 0.6931471805599453f
#define DNSCALE 0.18033688011112042f     // 0.125 * log2(e)

typedef __attribute__((ext_vector_type(8))) short bf16x8;
typedef __attribute__((ext_vector_type(4))) float f32x4;

#if __has_builtin(__builtin_amdgcn_exp2f)
#define EXP2(x) __builtin_amdgcn_exp2f(x)
#else
#define EXP2(x) exp2f(x)
#endif
#if __has_builtin(__builtin_amdgcn_logf)
#define LOG2(x) __builtin_amdgcn_logf(x)
#else
#define LOG2(x) __log2f(x)
#endif

__device__ __forceinline__ unsigned short f2bf(float f){
    union { float f; unsigned int i; } u; u.f = f;
    unsigned int r = u.i + 0x7FFFu + ((u.i >> 16) & 1u);   // RNE
    return (unsigned short)(r >> 16);
}
__device__ __forceinline__ float bf2f(unsigned short s){
    union { unsigned int i; float f; } u; u.i = ((unsigned int)s) << 16;
    return u.f;
}
// pack two fp32 -> [hi:lo] bf16 pair, half-up rounding (1 add each + v_perm)
__device__ __forceinline__ unsigned int pack_bf2(float lo, float hi){
    unsigned int i0 = __float_as_uint(lo) + 0x8000u;
    unsigned int i1 = __float_as_uint(hi) + 0x8000u;
    return __builtin_amdgcn_perm(i1, i0, 0x07060302u);
}

// async global->LDS, 16B per lane; LDS dest = wave-uniform base + lane*16
__device__ __forceinline__ void gload_lds16(const void* g, void* l){
    __builtin_amdgcn_global_load_lds(
        (const __attribute__((address_space(1))) void*)g,
        (__attribute__((address_space(3))) void*)l, 16, 0, 0);
}

// ---------------- fused prep: 4 weight transposes + X convert + bias pack ----------------
__global__ __launch_bounds__(256) void prep_kernel(
    const float* __restrict__ X,
    const float* __restrict__ Wq, const float* __restrict__ Wk,
    const float* __restrict__ Wv, const float* __restrict__ Wo,
    const float* __restrict__ bq, const float* __restrict__ bk,
    const float* __restrict__ bv,
    unsigned short* __restrict__ Xb, unsigned short* __restrict__ WqkvT,
    unsigned short* __restrict__ WoT, float* __restrict__ qkvb)
{
    __shared__ float t[32][33];
    int b = blockIdx.x;
    const int tid = threadIdx.x;

    if (b >= 10240){
        if (b < 10752){   // X fp32 -> bf16, 8/thread
            int i = ((b - 10240) * 256 + tid) * 8;
            float4 a = *(const float4*)&X[i];
            float4 c = *(const float4*)&X[i + 4];
            union { unsigned short u[8]; uint4 v; } o;
            o.u[0]=f2bf(a.x); o.u[1]=f2bf(a.y); o.u[2]=f2bf(a.z); o.u[3]=f2bf(a.w);
            o.u[4]=f2bf(c.x); o.u[5]=f2bf(c.y); o.u[6]=f2bf(c.z); o.u[7]=f2bf(c.w);
            *(uint4*)&Xb[i] = o.v;
        } else {          // bias pack
            int i = (b - 10752) * 256 + tid;
            float v;
            if (i < 4096) v = bq[i];
            else if (i < 5120) v = bk[i - 4096];
            else v = bv[i - 5120];
            qkvb[i] = v;
        }
        return;
    }

    const float* W; unsigned short* Wt; int N, tiles_x;
    if (b < 4096)      { W = Wq; Wt = WqkvT;                       N = 4096; tiles_x = 128; }
    else if (b < 5120) { b -= 4096; W = Wk; Wt = WqkvT + (size_t)4096*1024; N = 1024; tiles_x = 32; }
    else if (b < 9216) { b -= 5120; W = Wv; Wt = WqkvT + (size_t)5120*1024; N = 4096; tiles_x = 128; }
    else               { b -= 9216; W = Wo; Wt = WoT;              N = 1024; tiles_x = 32; }

    const int k0 = (b / tiles_x) * 32, n0 = (b % tiles_x) * 32;
    const int r = tid >> 3, c4 = (tid & 7) * 4;
    float4 v = *(const float4*)&W[(size_t)(k0 + r) * N + n0 + c4];
    t[c4+0][r] = v.x; t[c4+1][r] = v.y; t[c4+2][r] = v.z; t[c4+3][r] = v.w;
    __syncthreads();
    union { unsigned short u[4]; uint2 v; } o;
    o.u[0]=f2bf(t[r][c4+0]); o.u[1]=f2bf(t[r][c4+1]);
    o.u[2]=f2bf(t[r][c4+2]); o.u[3]=f2bf(t[r][c4+3]);
    *(uint2*)&Wt[(size_t)(n0 + r) * 1024 + k0 + c4] = o.v;
}

// ---------------- bf16 MFMA GEMM (m97-style): C = A[M,K] @ Bt[N,K]^T + bias ----------------
template<int BM, int BN, int OUTBF>
__global__ __launch_bounds__(256) void gemm_k(
    const unsigned short* __restrict__ A,
    const unsigned short* __restrict__ Bt,
    const float* __restrict__ bias,
    void* __restrict__ Cout, int M, int N, int K)
{
    constexpr int MT = BM / 32;
    constexpr int NT = BN / 32;
    __shared__ unsigned short As[BM * 64];
    __shared__ unsigned short Bs[BN * 64];
    const int tid  = threadIdx.x;
    const int wave = tid >> 6;
    const int lane = tid & 63;
    const int l15  = lane & 15;
    const int quad = lane >> 4;
    const int m0 = blockIdx.y * BM;
    const int n0 = blockIdx.x * BN;
    const int wm = (wave >> 1) * (BM / 2);
    const int wn = (wave & 1) * (BN / 2);

    f32x4 acc[MT][NT];
    #pragma unroll
    for (int i = 0; i < MT; i++)
        #pragma unroll
        for (int j = 0; j < NT; j++)
            acc[i][j] = (f32x4){0.f, 0.f, 0.f, 0.f};

    for (int k0 = 0; k0 < K; k0 += 64){
        #pragma unroll
        for (int j = 0; j < (BM * 8) / 256; j++){
            int bslot = j * 256 + wave * 64;
            int slot = bslot + lane;
            int row = slot >> 3, phys = slot & 7;
            int c = phys ^ (row & 7);
            gload_lds16(&A[(size_t)(m0 + row) * K + k0 + c * 8], &As[bslot * 8]);
        }
        #pragma unroll
        for (int j = 0; j < (BN * 8) / 256; j++){
            int bslot = j * 256 + wave * 64;
            int slot = bslot + lane;
            int row = slot >> 3, phys = slot & 7;
            int c = phys ^ (row & 7);
            gload_lds16(&Bt[(size_t)(n0 + row) * K + k0 + c * 8], &Bs[bslot * 8]);
        }
        __syncthreads();
        #pragma unroll
        for (int ks = 0; ks < 2; ks++){
            bf16x8 af[MT], bfr[NT];
            #pragma unroll
            for (int i = 0; i < MT; i++){
                int row = wm + i * 16 + l15;
                int phys = (ks * 4 + quad) ^ (row & 7);
                af[i] = *(const bf16x8*)&As[row * 64 + phys * 8];
            }
            #pragma unroll
            for (int j = 0; j < NT; j++){
                int row = wn + j * 16 + l15;
                int phys = (ks * 4 + quad) ^ (row & 7);
                bfr[j] = *(const bf16x8*)&Bs[row * 64 + phys * 8];
            }
            #pragma unroll
            for (int i = 0; i < MT; i++)
                #pragma unroll
                for (int j = 0; j < NT; j++)
                    acc[i][j] = __builtin_amdgcn_mfma_f32_16x16x32_bf16(af[i], bfr[j], acc[i][j], 0, 0, 0);
        }
        __syncthreads();
    }
    #pragma unroll
    for (int i = 0; i < MT; i++){
        #pragma unroll
        for (int j = 0; j < NT; j++){
            int col = n0 + wn + j * 16 + l15;
            float bv = bias[col];
            #pragma unroll
            for (int r = 0; r < 4; r++){
                int row = m0 + wm + i * 16 + quad * 4 + r;
                float v = acc[i][j][r] + bv;
                if (OUTBF) ((unsigned short*)Cout)[(size_t)row * N + col] = f2bf(v);
                else       ((float*)Cout)[(size_t)row * N + col] = v;
            }
        }
    }
}

// ---------------- RoPE (Q + K fused) ----------------
__global__ void rope_kernel(unsigned short* __restrict__ qkv, float* __restrict__ dninv)
{
    int idx = blockIdx.x * blockDim.x + threadIdx.x;   // 81920
    if (idx < 65536){   // Q: (t, h 0..63)
        int t = idx >> 6, h = idx & 63;
        unsigned short* p = qkv + (size_t)t * QKV_N + h * 64;
        uint4 raw[8];
        #pragma unroll
        for (int i = 0; i < 8; i++) raw[i] = *(const uint4*)(p + i * 8);
        const unsigned short* rp = (const unsigned short*)raw;
        float x[64];
        #pragma unroll
        for (int i = 0; i < 64; i++) x[i] = bf2f(rp[i]);
        unsigned short o[64];
        #pragma unroll
        for (int d = 0; d < 32; d++){
            float inv = EXP2(-(float)d * 0.4152410118609203f);   // log2(1e4)/32
            float s, c; __sincosf((float)t * inv, &s, &c);
            float x1 = x[2*d], x2 = x[2*d+1];
            o[d]      = f2bf(x1 * c - x2 * s);
            o[d + 32] = f2bf(x1 * s + x2 * c);
        }
        #pragma unroll
        for (int i = 0; i < 8; i++) *(uint4*)(p + i * 8) = ((const uint4*)o)[i];
    } else {            // K: (t, kh 0..15) + log2e*0.125/||k||
        idx -= 65536;
        int t = idx >> 4, h = idx & 15;
        unsigned short* p = qkv + (size_t)t * QKV_N + 4096 + h * 64;
        uint4 raw[8];
        #pragma unroll
        for (int i = 0; i < 8; i++) raw[i] = *(const uint4*)(p + i * 8);
        const unsigned short* rp = (const unsigned short*)raw;
        float x[64];
        #pragma unroll
        for (int i = 0; i < 64; i++) x[i] = bf2f(rp[i]);
        unsigned short o[64];
        float ss = 0.f;
        #pragma unroll
        for (int d = 0; d < 32; d++){
            float inv = EXP2(-(float)d * 0.4152410118609203f);
            float s, c; __sincosf((float)t * inv, &s, &c);
            float x1 = x[2*d], x2 = x[2*d+1];
            float a = x1 * c - x2 * s;
            float b = x1 * s + x2 * c;
            ss = fmaf(a, a, fmaf(b, b, ss));
            o[d]      = f2bf(a);
            o[d + 32] = f2bf(b);
        }
        #pragma unroll
        for (int i = 0; i < 8; i++) *(uint4*)(p + i * 8) = ((const uint4*)o)[i];
        dninv[h * 1024 + t] = DNSCALE * rsqrtf(fmaxf(ss, 1e-6f));
    }
}

// ---------------- fused attention ----------------
// grid (pi 0..7, h 0..63); 512 thr = 8 waves. Waves 0-3: qt=pi; waves 4-7: qt=15-pi.
// S^T orientation: mfma(kf, qf) -> lane owns 4 consecutive s for one q.
__global__ __launch_bounds__(512) void attn_mfma(
    const unsigned short* __restrict__ qkv,
    const float* __restrict__ dninv,
    const float* __restrict__ sinks, const float* __restrict__ vnulls,
    unsigned short* __restrict__ ctx)       // [64][1024][64] bf16
{
    __shared__ unsigned short ks[64 * 64];          // [s][chunk ^ (s&7)]
    __shared__ unsigned short vt[64 * 64];          // [d][chunk ^ ((d^(d>>3))&7)]
    __shared__ unsigned short ws[2][64][72];        // P [tile][q][s]
    __shared__ float dl[64];
    __shared__ float dsum[8][16];

    const int tid  = threadIdx.x;
    const int wave = tid >> 6;          // 0..7
    const int tile = wave >> 2;         // 0=A, 1=B
    const int w    = wave & 3;          // row-block in tile
    const int lane = tid & 63;
    const int l15  = lane & 15;
    const int quad = lane >> 4;
    const int h  = blockIdx.y;
    const int kh = h & 15;
    const int pi = blockIdx.x;
    const int qtB = 15 - pi;
    const int qt  = tile ? qtB : pi;
    const int t0  = qt << 6;

    const unsigned short* Q  = qkv;
    const unsigned short* Kp = qkv + 4096;
    const unsigned short* V  = qkv + 5120;

    bf16x8 qf0, qf1;
    {
        const unsigned short* qp = Q + (size_t)(t0 + w * 16 + l15) * QKV_N + h * 64;
        qf0 = *(const bf16x8*)(qp + quad * 8);
        qf1 = *(const bf16x8*)(qp + 32 + quad * 8);
    }

    f32x4 acc_o[4];
    #pragma unroll
    for (int i = 0; i < 4; i++) acc_o[i] = (f32x4){0.f, 0.f, 0.f, 0.f};
    float den = 0.f;                    // per-lane, q = w*16 + l15
    const int q_glob = t0 + w * 16 + l15;

    const int pr  = (tid & 255) >> 3;   // V staging (threads 0..255)
    const int cch = tid & 7;

    for (int st = 0; st <= qtB; st++){
        const int s0 = st << 6;
        __syncthreads();                // previous iteration's LDS reads done

        {   // K tile: one async global_load_lds per wave
            int bslot = wave * 64;
            int slot = bslot + lane;
            int row = slot >> 3, phys = slot & 7;
            int c = phys ^ (row & 7);
            gload_lds16(&Kp[(size_t)(s0 + row) * QKV_N + kh * 64 + c * 8], &ks[bslot * 8]);
        }
        if (tid < 256){                 // V tile transposed, packed-pair b32 writes
            uint4 g0 = *(const uint4*)&V[(size_t)(s0 + 2 * pr)     * QKV_N + h * 64 + cch * 8];
            uint4 g1 = *(const uint4*)&V[(size_t)(s0 + 2 * pr + 1) * QKV_N + h * 64 + cch * 8];
            const unsigned short* p0 = (const unsigned short*)&g0;
            const unsigned short* p1 = (const unsigned short*)&g1;
            #pragma unroll
            for (int j = 0; j < 8; j++){
                int d = cch * 8 + j;
                int physc = (pr >> 2) ^ ((d ^ (d >> 3)) & 7);
                unsigned int val = (unsigned int)p0[j] | ((unsigned int)p1[j] << 16);
                ((unsigned int*)vt)[d * 32 + physc * 4 + (pr & 3)] = val;
            }
        } else if (tid < 320){
            dl[tid - 256] = dninv[kh * 1024 + s0 + (tid - 256)];
        }
        __syncthreads();

        if (st > qt) continue;          // tile-A waves keep staging for tile B
        const bool diag = (st == qt);

        // S^T: mfma(kf, qf) -> row (quad*4+r) = s-sub, col l15 = q
        #pragma unroll
        for (int nt = 0; nt < 4; nt++){
            const int sbase = nt * 16 + quad * 4;
            uint2* wp = (uint2*)&ws[tile][w * 16 + l15][sbase];
            if (diag && nt > w){ *wp = (uint2){0u, 0u}; continue; }

            f32x4 sc = (f32x4){0.f, 0.f, 0.f, 0.f};
            {
                int srow = nt * 16 + l15;
                int ph0 = quad ^ (srow & 7);
                int ph1 = (4 + quad) ^ (srow & 7);
                bf16x8 kf0 = *(const bf16x8*)&ks[srow * 64 + ph0 * 8];
                bf16x8 kf1 = *(const bf16x8*)&ks[srow * 64 + ph1 * 8];
                sc = __builtin_amdgcn_mfma_f32_16x16x32_bf16(kf0, qf0, sc, 0, 0, 0);
                sc = __builtin_amdgcn_mfma_f32_16x16x32_bf16(kf1, qf1, sc, 0, 0, 0);
            }
            float da[4];
            *(float4*)da = *(const float4*)&dl[sbase];
            float w4[4];
            #pragma unroll
            for (int r = 0; r < 4; r++){
                float y = sc[r] * da[r];                      // x * log2(e)
                float p = EXP2(-fabsf(y));
                float u = fmaxf(y, 0.f) + LOG2(1.f + p);      // softplus * log2(e)
                float e3 = EXP2(-SILU_SCALE * u);             // == exp(-SCALE*softplus)
                float wv = __fdividef(LN2 * u, 1.f + e3);
                wv = (s0 + sbase + r <= q_glob) ? wv : 0.f;
                den += wv;
                w4[r] = wv;
            }
            uint2 pk;
            pk.x = pack_bf2(w4[0], w4[1]);
            pk.y = pack_bf2(w4[2], w4[3]);
            *wp = pk;
        }

        // PV (wave-private ws rows)
        {
            const int prow = w * 16 + l15;
            bf16x8 pf0 = *(const bf16x8*)&ws[tile][prow][quad * 8];
            bf16x8 pf1 = *(const bf16x8*)&ws[tile][prow][32 + quad * 8];
            const bool skip_hi = diag && (w <= 1);   // s>=32 all masked
            #pragma unroll
            for (int dt = 0; dt < 4; dt++){
                int d = dt * 16 + l15;
                int swz = (d ^ (d >> 3)) & 7;
                bf16x8 vf0 = *(const bf16x8*)&vt[d * 64 + (quad ^ swz) * 8];
                acc_o[dt] = __builtin_amdgcn_mfma_f32_16x16x32_bf16(pf0, vf0, acc_o[dt], 0, 0, 0);
                if (!skip_hi){
                    bf16x8 vf1 = *(const bf16x8*)&vt[d * 64 + ((4 + quad) ^ swz) * 8];
                    acc_o[dt] = __builtin_amdgcn_mfma_f32_16x16x32_bf16(pf1, vf1, acc_o[dt], 0, 0, 0);
                }
            }
        }
    }

    // denominator: reduce across quads (same q = l15), redistribute via LDS
    den += __shfl_xor(den, 16);
    den += __shfl_xor(den, 32);
    if (quad == 0) dsum[wave][l15] = den;
    float den4[4];
    *(float4*)den4 = *(const float4*)&dsum[wave][quad * 4];

    float sinkv = tanhf(sinks[h]) + 1e-6f;
    #pragma unroll
    for (int r = 0; r < 4; r++){
        int qg = t0 + w * 16 + quad * 4 + r;
        float alpha = __fdividef(1.f, den4[r] + sinkv + 1e-6f);
        #pragma unroll
        for (int dt = 0; dt < 4; dt++){
            int d = dt * 16 + l15;
            float o = (acc_o[dt][r] + sinkv * vnulls[h * 64 + d]) * alpha;
            ctx[((size_t)h * 1024 + qg) * 64 + d] = f2bf(o);
        }
    }
}

// avg over 4 branches -> bf16 [t][nh*64+d], 8 elems/thread
__global__ void avg_kernel(const unsigned short* __restrict__ ctx, unsigned short* __restrict__ avg)
{
    int i8 = (blockIdx.x * 256 + threadIdx.x) * 8;   // 1M elements
    int t = i8 >> 10, c = i8 & 1023;
    int nh = c >> 6, d = c & 63;
    float s[8] = {};
    #pragma unroll
    for (int br = 0; br < 4; br++){
        uint4 v = *(const uint4*)&ctx[((size_t)(br * 16 + nh) * 1024 + t) * 64 + d];
        const unsigned short* p = (const unsigned short*)&v;
        #pragma unroll
        for (int j = 0; j < 8; j++) s[j] += bf2f(p[j]);
    }
    union { unsigned short u[8]; uint4 v; } o;
    #pragma unroll
    for (int j = 0; j < 8; j++) o.u[j] = f2bf(0.25f * s[j]);
    *(uint4*)&avg[i8] = o.v;
}

extern "C" void kernel_launch(void* const* d_in, const int* in_sizes, int n_in,
                              void* d_out, int out_size, void* d_ws, size_t ws_size,
                              hipStream_t stream)
{
    (void)in_sizes; (void)n_in; (void)out_size; (void)ws_size;
    const float* X      = (const float*)d_in[0];
    const float* Wq     = (const float*)d_in[1];
    const float* bq     = (const float*)d_in[2];
    const float* Wk     = (const float*)d_in[3];
    const float* bk     = (const float*)d_in[4];
    const float* Wv     = (const float*)d_in[5];
    const float* bv     = (const float*)d_in[6];
    const float* sinks  = (const float*)d_in[7];
    const float* vnulls = (const float*)d_in[8];
    const float* Wo     = (const float*)d_in[9];
    const float* bo     = (const float*)d_in[10];
    float* out = (float*)d_out;

    unsigned short* w16   = (unsigned short*)d_ws;
    unsigned short* Xb    = w16;                                  // 1M
    unsigned short* WqkvT = Xb    + (size_t)1024 * 1024;          // 9216*1024
    unsigned short* QKVb  = WqkvT + (size_t)QKV_N * 1024;         // 1024*9216
    unsigned short* WoT   = QKVb  + (size_t)1024 * QKV_N;         // 1M
    unsigned short* ctxb  = WoT   + (size_t)1024 * 1024;          // 4M
    unsigned short* avgb  = ctxb  + (size_t)64 * 1024 * 64;       // 1M
    float* qkvb = (float*)(avgb + (size_t)1024 * 1024);           // 9216
    float* dnf  = qkvb + QKV_N;                                   // 16*1024

    dim3 blk(256);
    prep_kernel<<<10788, blk, 0, stream>>>(X, Wq, Wk, Wv, Wo, bq, bk, bv,
                                           Xb, WqkvT, WoT, qkvb);
    gemm_k<128, 96, 1><<<dim3(96, 8), blk, 0, stream>>>(Xb, WqkvT, qkvb, QKVb, 1024, QKV_N, 1024);
    rope_kernel<<<320, blk, 0, stream>>>(QKVb, dnf);
    attn_mfma<<<dim3(8, 64), dim3(512), 0, stream>>>(QKVb, dnf, sinks, vnulls, ctxb);
    avg_kernel<<<512, blk, 0, stream>>>(ctxb, avgb);
    gemm_k<64, 64, 0><<<dim3(16, 16), blk, 0, stream>>>(avgb, WoT, bo, out, 1024, 1024, 1024);
}

// Round 5
// 209.176 us; speedup vs baseline: 4.9127x; 1.0177x over previous
//
#include <hip/hip_runtime.h>
#include <math.h>

#define SILU_SCALE 1.8137993642342178f   // pi/sqrt(3)
#define QKV_N 9216                       // 4096 Q | 1024 K | 4096 V
#define LN2 0.6931471805599453f
#define DNSCALE 0.18033688011112042f     // 0.125 * log2(e)

typedef __attribute__((ext_vector_type(8))) short bf16x8;
typedef __attribute__((ext_vector_type(4))) float f32x4;

#if __has_builtin(__builtin_amdgcn_exp2f)
#define EXP2(x) __builtin_amdgcn_exp2f(x)
#else
#define EXP2(x) exp2f(x)
#endif
#if __has_builtin(__builtin_amdgcn_logf)
#define LOG2(x) __builtin_amdgcn_logf(x)
#else
#define LOG2(x) __log2f(x)
#endif

__device__ __forceinline__ unsigned short f2bf(float f){
    union { float f; unsigned int i; } u; u.f = f;
    unsigned int r = u.i + 0x7FFFu + ((u.i >> 16) & 1u);   // RNE
    return (unsigned short)(r >> 16);
}
__device__ __forceinline__ float bf2f(unsigned short s){
    union { unsigned int i; float f; } u; u.i = ((unsigned int)s) << 16;
    return u.f;
}
// pack two fp32 -> [hi:lo] bf16 pair, half-up rounding (1 add each + v_perm)
__device__ __forceinline__ unsigned int pack_bf2(float lo, float hi){
    unsigned int i0 = __float_as_uint(lo) + 0x8000u;
    unsigned int i1 = __float_as_uint(hi) + 0x8000u;
    return __builtin_amdgcn_perm(i1, i0, 0x07060302u);
}

// async global->LDS, 16B per lane; LDS dest = wave-uniform base + lane*16
__device__ __forceinline__ void gload_lds16(const void* g, void* l){
    __builtin_amdgcn_global_load_lds(
        (const __attribute__((address_space(1))) void*)g,
        (__attribute__((address_space(3))) void*)l, 16, 0, 0);
}

// ---------------- fused prep: 4 weight transposes (64x64 tiles) + X convert + bias ----------------
// blocks: [0,1024) Wq | [1024,1280) Wk | [1280,2304) Wv | [2304,2560) Wo |
//         [2560,3072) X conv | [3072,3108) bias
__global__ __launch_bounds__(256) void prep_kernel(
    const float* __restrict__ X,
    const float* __restrict__ Wq, const float* __restrict__ Wk,
    const float* __restrict__ Wv, const float* __restrict__ Wo,
    const float* __restrict__ bq, const float* __restrict__ bk,
    const float* __restrict__ bv,
    unsigned short* __restrict__ Xb, unsigned short* __restrict__ WqkvT,
    unsigned short* __restrict__ WoT, float* __restrict__ qkvb)
{
    __shared__ float t[64][65];
    int b = blockIdx.x;
    const int tid = threadIdx.x;

    if (b >= 2560){
        if (b < 3072){   // X fp32 -> bf16, 8/thread
            int i = ((b - 2560) * 256 + tid) * 8;
            float4 a = *(const float4*)&X[i];
            float4 c = *(const float4*)&X[i + 4];
            union { unsigned short u[8]; uint4 v; } o;
            o.u[0]=f2bf(a.x); o.u[1]=f2bf(a.y); o.u[2]=f2bf(a.z); o.u[3]=f2bf(a.w);
            o.u[4]=f2bf(c.x); o.u[5]=f2bf(c.y); o.u[6]=f2bf(c.z); o.u[7]=f2bf(c.w);
            *(uint4*)&Xb[i] = o.v;
        } else {          // bias pack
            int i = (b - 3072) * 256 + tid;
            float v;
            if (i < 4096) v = bq[i];
            else if (i < 5120) v = bk[i - 4096];
            else v = bv[i - 5120];
            qkvb[i] = v;
        }
        return;
    }

    const float* W; unsigned short* Wt; int N, tiles_x;
    if (b < 1024)      { W = Wq; Wt = WqkvT;                       N = 4096; tiles_x = 64; }
    else if (b < 1280) { b -= 1024; W = Wk; Wt = WqkvT + (size_t)4096*1024; N = 1024; tiles_x = 16; }
    else if (b < 2304) { b -= 1280; W = Wv; Wt = WqkvT + (size_t)5120*1024; N = 4096; tiles_x = 64; }
    else               { b -= 2304; W = Wo; Wt = WoT;              N = 1024; tiles_x = 16; }

    const int k0 = (b / tiles_x) * 64, n0 = (b % tiles_x) * 64;
    const int lr  = tid >> 4;          // 0..15
    const int lc4 = (tid & 15) * 4;    // 0..60
    #pragma unroll
    for (int p = 0; p < 4; p++){
        int r = lr + p * 16;
        float4 v = *(const float4*)&W[(size_t)(k0 + r) * N + n0 + lc4];
        t[lc4+0][r] = v.x; t[lc4+1][r] = v.y;
        t[lc4+2][r] = v.z; t[lc4+3][r] = v.w;
    }
    __syncthreads();
    const int wr  = tid >> 3;          // 0..31
    const int wc8 = (tid & 7) * 8;     // 0..56
    #pragma unroll
    for (int p = 0; p < 2; p++){
        int r = wr + p * 32;
        union { unsigned short u[8]; uint4 v; } o;
        #pragma unroll
        for (int j = 0; j < 8; j++) o.u[j] = f2bf(t[r][wc8 + j]);
        *(uint4*)&Wt[(size_t)(n0 + r) * 1024 + k0 + wc8] = o.v;
    }
}

// ---------------- bf16 MFMA GEMM (m97-style): C = A[M,K] @ Bt[N,K]^T + bias ----------------
template<int BM, int BN, int OUTBF>
__global__ __launch_bounds__(256) void gemm_k(
    const unsigned short* __restrict__ A,
    const unsigned short* __restrict__ Bt,
    const float* __restrict__ bias,
    void* __restrict__ Cout, int M, int N, int K)
{
    constexpr int MT = BM / 32;
    constexpr int NT = BN / 32;
    __shared__ unsigned short As[BM * 64];
    __shared__ unsigned short Bs[BN * 64];
    const int tid  = threadIdx.x;
    const int wave = tid >> 6;
    const int lane = tid & 63;
    const int l15  = lane & 15;
    const int quad = lane >> 4;
    const int m0 = blockIdx.y * BM;
    const int n0 = blockIdx.x * BN;
    const int wm = (wave >> 1) * (BM / 2);
    const int wn = (wave & 1) * (BN / 2);

    f32x4 acc[MT][NT];
    #pragma unroll
    for (int i = 0; i < MT; i++)
        #pragma unroll
        for (int j = 0; j < NT; j++)
            acc[i][j] = (f32x4){0.f, 0.f, 0.f, 0.f};

    for (int k0 = 0; k0 < K; k0 += 64){
        #pragma unroll
        for (int j = 0; j < (BM * 8) / 256; j++){
            int bslot = j * 256 + wave * 64;
            int slot = bslot + lane;
            int row = slot >> 3, phys = slot & 7;
            int c = phys ^ (row & 7);
            gload_lds16(&A[(size_t)(m0 + row) * K + k0 + c * 8], &As[bslot * 8]);
        }
        #pragma unroll
        for (int j = 0; j < (BN * 8) / 256; j++){
            int bslot = j * 256 + wave * 64;
            int slot = bslot + lane;
            int row = slot >> 3, phys = slot & 7;
            int c = phys ^ (row & 7);
            gload_lds16(&Bt[(size_t)(n0 + row) * K + k0 + c * 8], &Bs[bslot * 8]);
        }
        __syncthreads();
        #pragma unroll
        for (int ks = 0; ks < 2; ks++){
            bf16x8 af[MT], bfr[NT];
            #pragma unroll
            for (int i = 0; i < MT; i++){
                int row = wm + i * 16 + l15;
                int phys = (ks * 4 + quad) ^ (row & 7);
                af[i] = *(const bf16x8*)&As[row * 64 + phys * 8];
            }
            #pragma unroll
            for (int j = 0; j < NT; j++){
                int row = wn + j * 16 + l15;
                int phys = (ks * 4 + quad) ^ (row & 7);
                bfr[j] = *(const bf16x8*)&Bs[row * 64 + phys * 8];
            }
            #pragma unroll
            for (int i = 0; i < MT; i++)
                #pragma unroll
                for (int j = 0; j < NT; j++)
                    acc[i][j] = __builtin_amdgcn_mfma_f32_16x16x32_bf16(af[i], bfr[j], acc[i][j], 0, 0, 0);
        }
        __syncthreads();
    }
    #pragma unroll
    for (int i = 0; i < MT; i++){
        #pragma unroll
        for (int j = 0; j < NT; j++){
            int col = n0 + wn + j * 16 + l15;
            float bv = bias[col];
            #pragma unroll
            for (int r = 0; r < 4; r++){
                int row = m0 + wm + i * 16 + quad * 4 + r;
                float v = acc[i][j][r] + bv;
                if (OUTBF) ((unsigned short*)Cout)[(size_t)row * N + col] = f2bf(v);
                else       ((float*)Cout)[(size_t)row * N + col] = v;
            }
        }
    }
}

// ---------------- Wo GEMM, split-K=2: P[z] = A[:, z*512:+512] @ Bt[:, same]^T (fp32) ----------------
// grid (16, 8, 2): 128x64 tiles, 1 block/CU exact
__global__ __launch_bounds__(256) void gemm_wo(
    const unsigned short* __restrict__ A,    // avgb [1024][1024] bf16
    const unsigned short* __restrict__ Bt,   // WoT  [1024][1024] bf16
    float* __restrict__ P)                   // [2][1024][1024] fp32 partials
{
    constexpr int BM = 128, BN = 64, MT = 4, NT = 2;
    __shared__ unsigned short As[BM * 64];
    __shared__ unsigned short Bs[BN * 64];
    const int tid  = threadIdx.x;
    const int wave = tid >> 6;
    const int lane = tid & 63;
    const int l15  = lane & 15;
    const int quad = lane >> 4;
    const int m0 = blockIdx.y * BM;
    const int n0 = blockIdx.x * BN;
    const int kz = blockIdx.z;
    const int wm = (wave >> 1) * 64;
    const int wn = (wave & 1) * 32;

    f32x4 acc[MT][NT];
    #pragma unroll
    for (int i = 0; i < MT; i++)
        #pragma unroll
        for (int j = 0; j < NT; j++)
            acc[i][j] = (f32x4){0.f, 0.f, 0.f, 0.f};

    const int kbeg = kz * 512;
    for (int k0 = kbeg; k0 < kbeg + 512; k0 += 64){
        #pragma unroll
        for (int j = 0; j < (BM * 8) / 256; j++){
            int bslot = j * 256 + wave * 64;
            int slot = bslot + lane;
            int row = slot >> 3, phys = slot & 7;
            int c = phys ^ (row & 7);
            gload_lds16(&A[(size_t)(m0 + row) * 1024 + k0 + c * 8], &As[bslot * 8]);
        }
        #pragma unroll
        for (int j = 0; j < (BN * 8) / 256; j++){
            int bslot = j * 256 + wave * 64;
            int slot = bslot + lane;
            int row = slot >> 3, phys = slot & 7;
            int c = phys ^ (row & 7);
            gload_lds16(&Bt[(size_t)(n0 + row) * 1024 + k0 + c * 8], &Bs[bslot * 8]);
        }
        __syncthreads();
        #pragma unroll
        for (int ks = 0; ks < 2; ks++){
            bf16x8 af[MT], bfr[NT];
            #pragma unroll
            for (int i = 0; i < MT; i++){
                int row = wm + i * 16 + l15;
                int phys = (ks * 4 + quad) ^ (row & 7);
                af[i] = *(const bf16x8*)&As[row * 64 + phys * 8];
            }
            #pragma unroll
            for (int j = 0; j < NT; j++){
                int row = wn + j * 16 + l15;
                int phys = (ks * 4 + quad) ^ (row & 7);
                bfr[j] = *(const bf16x8*)&Bs[row * 64 + phys * 8];
            }
            #pragma unroll
            for (int i = 0; i < MT; i++)
                #pragma unroll
                for (int j = 0; j < NT; j++)
                    acc[i][j] = __builtin_amdgcn_mfma_f32_16x16x32_bf16(af[i], bfr[j], acc[i][j], 0, 0, 0);
        }
        __syncthreads();
    }
    float* Pz = P + (size_t)kz * 1024 * 1024;
    #pragma unroll
    for (int i = 0; i < MT; i++){
        #pragma unroll
        for (int j = 0; j < NT; j++){
            int col = n0 + wn + j * 16 + l15;
            #pragma unroll
            for (int r = 0; r < 4; r++){
                int row = m0 + wm + i * 16 + quad * 4 + r;
                Pz[(size_t)row * 1024 + col] = acc[i][j][r];
            }
        }
    }
}

// out = P[0] + P[1] + bias  (fp32, 4/thread)
__global__ void wo_reduce(const float* __restrict__ P, const float* __restrict__ bo,
                          float* __restrict__ out)
{
    int i = (blockIdx.x * 256 + threadIdx.x) * 4;   // 1M floats
    float4 a = *(const float4*)&P[i];
    float4 b = *(const float4*)&P[1024 * 1024 + i];
    float4 c = *(const float4*)&bo[i & 1023];
    float4 o;
    o.x = a.x + b.x + c.x; o.y = a.y + b.y + c.y;
    o.z = a.z + b.z + c.z; o.w = a.w + b.w + c.w;
    *(float4*)&out[i] = o;
}

// ---------------- RoPE (Q + K fused) ----------------
__global__ void rope_kernel(unsigned short* __restrict__ qkv, float* __restrict__ dninv)
{
    int idx = blockIdx.x * blockDim.x + threadIdx.x;   // 81920
    if (idx < 65536){   // Q: (t, h 0..63)
        int t = idx >> 6, h = idx & 63;
        unsigned short* p = qkv + (size_t)t * QKV_N + h * 64;
        uint4 raw[8];
        #pragma unroll
        for (int i = 0; i < 8; i++) raw[i] = *(const uint4*)(p + i * 8);
        const unsigned short* rp = (const unsigned short*)raw;
        float x[64];
        #pragma unroll
        for (int i = 0; i < 64; i++) x[i] = bf2f(rp[i]);
        unsigned short o[64];
        #pragma unroll
        for (int d = 0; d < 32; d++){
            float inv = EXP2(-(float)d * 0.4152410118609203f);   // log2(1e4)/32
            float s, c; __sincosf((float)t * inv, &s, &c);
            float x1 = x[2*d], x2 = x[2*d+1];
            o[d]      = f2bf(x1 * c - x2 * s);
            o[d + 32] = f2bf(x1 * s + x2 * c);
        }
        #pragma unroll
        for (int i = 0; i < 8; i++) *(uint4*)(p + i * 8) = ((const uint4*)o)[i];
    } else {            // K: (t, kh 0..15) + log2e*0.125/||k||
        idx -= 65536;
        int t = idx >> 4, h = idx & 15;
        unsigned short* p = qkv + (size_t)t * QKV_N + 4096 + h * 64;
        uint4 raw[8];
        #pragma unroll
        for (int i = 0; i < 8; i++) raw[i] = *(const uint4*)(p + i * 8);
        const unsigned short* rp = (const unsigned short*)raw;
        float x[64];
        #pragma unroll
        for (int i = 0; i < 64; i++) x[i] = bf2f(rp[i]);
        unsigned short o[64];
        float ss = 0.f;
        #pragma unroll
        for (int d = 0; d < 32; d++){
            float inv = EXP2(-(float)d * 0.4152410118609203f);
            float s, c; __sincosf((float)t * inv, &s, &c);
            float x1 = x[2*d], x2 = x[2*d+1];
            float a = x1 * c - x2 * s;
            float b = x1 * s + x2 * c;
            ss = fmaf(a, a, fmaf(b, b, ss));
            o[d]      = f2bf(a);
            o[d + 32] = f2bf(b);
        }
        #pragma unroll
        for (int i = 0; i < 8; i++) *(uint4*)(p + i * 8) = ((const uint4*)o)[i];
        dninv[h * 1024 + t] = DNSCALE * rsqrtf(fmaxf(ss, 1e-6f));
    }
}

// ---------------- fused attention ----------------
// grid (pi 0..7, h 0..63); 512 thr = 8 waves. Waves 0-3: qt=pi; waves 4-7: qt=15-pi.
// S^T orientation: mfma(kf, qf) -> lane owns 4 consecutive s for one q.
__global__ __launch_bounds__(512) void attn_mfma(
    const unsigned short* __restrict__ qkv,
    const float* __restrict__ dninv,
    const float* __restrict__ sinks, const float* __restrict__ vnulls,
    unsigned short* __restrict__ ctx)       // [64][1024][64] bf16
{
    __shared__ unsigned short ks[64 * 64];          // [s][chunk ^ (s&7)]
    __shared__ unsigned short vt[64 * 64];          // [d][chunk ^ ((d^(d>>3))&7)]
    __shared__ unsigned short ws[2][64][72];        // P [tile][q][s]
    __shared__ float dl[64];
    __shared__ float dsum[8][16];

    const int tid  = threadIdx.x;
    const int wave = tid >> 6;          // 0..7
    const int tile = wave >> 2;         // 0=A, 1=B
    const int w    = wave & 3;          // row-block in tile
    const int lane = tid & 63;
    const int l15  = lane & 15;
    const int quad = lane >> 4;
    const int h  = blockIdx.y;
    const int kh = h & 15;
    const int pi = blockIdx.x;
    const int qtB = 15 - pi;
    const int qt  = tile ? qtB : pi;
    const int t0  = qt << 6;

    const unsigned short* Q  = qkv;
    const unsigned short* Kp = qkv + 4096;
    const unsigned short* V  = qkv + 5120;

    bf16x8 qf0, qf1;
    {
        const unsigned short* qp = Q + (size_t)(t0 + w * 16 + l15) * QKV_N + h * 64;
        qf0 = *(const bf16x8*)(qp + quad * 8);
        qf1 = *(const bf16x8*)(qp + 32 + quad * 8);
    }

    f32x4 acc_o[4];
    #pragma unroll
    for (int i = 0; i < 4; i++) acc_o[i] = (f32x4){0.f, 0.f, 0.f, 0.f};
    float den = 0.f;                    // per-lane, q = w*16 + l15
    const int q_glob = t0 + w * 16 + l15;

    const int pr  = (tid & 255) >> 3;   // V staging (threads 0..255)
    const int cch = tid & 7;

    for (int st = 0; st <= qtB; st++){
        const int s0 = st << 6;
        __syncthreads();                // previous iteration's LDS reads done

        {   // K tile: one async global_load_lds per wave
            int bslot = wave * 64;
            int slot = bslot + lane;
            int row = slot >> 3, phys = slot & 7;
            int c = phys ^ (row & 7);
            gload_lds16(&Kp[(size_t)(s0 + row) * QKV_N + kh * 64 + c * 8], &ks[bslot * 8]);
        }
        if (tid < 256){                 // V tile transposed, packed-pair b32 writes
            uint4 g0 = *(const uint4*)&V[(size_t)(s0 + 2 * pr)     * QKV_N + h * 64 + cch * 8];
            uint4 g1 = *(const uint4*)&V[(size_t)(s0 + 2 * pr + 1) * QKV_N + h * 64 + cch * 8];
            const unsigned short* p0 = (const unsigned short*)&g0;
            const unsigned short* p1 = (const unsigned short*)&g1;
            #pragma unroll
            for (int j = 0; j < 8; j++){
                int d = cch * 8 + j;
                int physc = (pr >> 2) ^ ((d ^ (d >> 3)) & 7);
                unsigned int val = (unsigned int)p0[j] | ((unsigned int)p1[j] << 16);
                ((unsigned int*)vt)[d * 32 + physc * 4 + (pr & 3)] = val;
            }
        } else if (tid < 320){
            dl[tid - 256] = dninv[kh * 1024 + s0 + (tid - 256)];
        }
        __syncthreads();

        if (st > qt) continue;          // tile-A waves keep staging for tile B
        const bool diag = (st == qt);

        // S^T: mfma(kf, qf) -> row (quad*4+r) = s-sub, col l15 = q
        #pragma unroll
        for (int nt = 0; nt < 4; nt++){
            const int sbase = nt * 16 + quad * 4;
            uint2* wp = (uint2*)&ws[tile][w * 16 + l15][sbase];
            if (diag && nt > w){ *wp = (uint2){0u, 0u}; continue; }

            f32x4 sc = (f32x4){0.f, 0.f, 0.f, 0.f};
            {
                int srow = nt * 16 + l15;
                int ph0 = quad ^ (srow & 7);
                int ph1 = (4 + quad) ^ (srow & 7);
                bf16x8 kf0 = *(const bf16x8*)&ks[srow * 64 + ph0 * 8];
                bf16x8 kf1 = *(const bf16x8*)&ks[srow * 64 + ph1 * 8];
                sc = __builtin_amdgcn_mfma_f32_16x16x32_bf16(kf0, qf0, sc, 0, 0, 0);
                sc = __builtin_amdgcn_mfma_f32_16x16x32_bf16(kf1, qf1, sc, 0, 0, 0);
            }
            float da[4];
            *(float4*)da = *(const float4*)&dl[sbase];
            float w4[4];
            #pragma unroll
            for (int r = 0; r < 4; r++){
                float y = sc[r] * da[r];                      // x * log2(e)
                float p = EXP2(-fabsf(y));
                float u = fmaxf(y, 0.f) + LOG2(1.f + p);      // softplus * log2(e)
                float e3 = EXP2(-SILU_SCALE * u);             // == exp(-SCALE*softplus)
                float wv = __fdividef(LN2 * u, 1.f + e3);
                wv = (s0 + sbase + r <= q_glob) ? wv : 0.f;
                den += wv;
                w4[r] = wv;
            }
            uint2 pk;
            pk.x = pack_bf2(w4[0], w4[1]);
            pk.y = pack_bf2(w4[2], w4[3]);
            *wp = pk;
        }

        // PV (wave-private ws rows)
        {
            const int prow = w * 16 + l15;
            bf16x8 pf0 = *(const bf16x8*)&ws[tile][prow][quad * 8];
            bf16x8 pf1 = *(const bf16x8*)&ws[tile][prow][32 + quad * 8];
            const bool skip_hi = diag && (w <= 1);   // s>=32 all masked
            #pragma unroll
            for (int dt = 0; dt < 4; dt++){
                int d = dt * 16 + l15;
                int swz = (d ^ (d >> 3)) & 7;
                bf16x8 vf0 = *(const bf16x8*)&vt[d * 64 + (quad ^ swz) * 8];
                acc_o[dt] = __builtin_amdgcn_mfma_f32_16x16x32_bf16(pf0, vf0, acc_o[dt], 0, 0, 0);
                if (!skip_hi){
                    bf16x8 vf1 = *(const bf16x8*)&vt[d * 64 + ((4 + quad) ^ swz) * 8];
                    acc_o[dt] = __builtin_amdgcn_mfma_f32_16x16x32_bf16(pf1, vf1, acc_o[dt], 0, 0, 0);
                }
            }
        }
    }

    // denominator: reduce across quads (same q = l15), redistribute via LDS
    den += __shfl_xor(den, 16);
    den += __shfl_xor(den, 32);
    if (quad == 0) dsum[wave][l15] = den;
    float den4[4];
    *(float4*)den4 = *(const float4*)&dsum[wave][quad * 4];

    float sinkv = tanhf(sinks[h]) + 1e-6f;
    #pragma unroll
    for (int r = 0; r < 4; r++){
        int qg = t0 + w * 16 + quad * 4 + r;
        float alpha = __fdividef(1.f, den4[r] + sinkv + 1e-6f);
        #pragma unroll
        for (int dt = 0; dt < 4; dt++){
            int d = dt * 16 + l15;
            float o = (acc_o[dt][r] + sinkv * vnulls[h * 64 + d]) * alpha;
            ctx[((size_t)h * 1024 + qg) * 64 + d] = f2bf(o);
        }
    }
}

// avg over 4 branches -> bf16 [t][nh*64+d], 8 elems/thread
__global__ void avg_kernel(const unsigned short* __restrict__ ctx, unsigned short* __restrict__ avg)
{
    int i8 = (blockIdx.x * 256 + threadIdx.x) * 8;   // 1M elements
    int t = i8 >> 10, c = i8 & 1023;
    int nh = c >> 6, d = c & 63;
    float s[8] = {};
    #pragma unroll
    for (int br = 0; br < 4; br++){
        uint4 v = *(const uint4*)&ctx[((size_t)(br * 16 + nh) * 1024 + t) * 64 + d];
        const unsigned short* p = (const unsigned short*)&v;
        #pragma unroll
        for (int j = 0; j < 8; j++) s[j] += bf2f(p[j]);
    }
    union { unsigned short u[8]; uint4 v; } o;
    #pragma unroll
    for (int j = 0; j < 8; j++) o.u[j] = f2bf(0.25f * s[j]);
    *(uint4*)&avg[i8] = o.v;
}

extern "C" void kernel_launch(void* const* d_in, const int* in_sizes, int n_in,
                              void* d_out, int out_size, void* d_ws, size_t ws_size,
                              hipStream_t stream)
{
    (void)in_sizes; (void)n_in; (void)out_size; (void)ws_size;
    const float* X      = (const float*)d_in[0];
    const float* Wq     = (const float*)d_in[1];
    const float* bq     = (const float*)d_in[2];
    const float* Wk     = (const float*)d_in[3];
    const float* bk     = (const float*)d_in[4];
    const float* Wv     = (const float*)d_in[5];
    const float* bv     = (const float*)d_in[6];
    const float* sinks  = (const float*)d_in[7];
    const float* vnulls = (const float*)d_in[8];
    const float* Wo     = (const float*)d_in[9];
    const float* bo     = (const float*)d_in[10];
    float* out = (float*)d_out;

    unsigned short* w16   = (unsigned short*)d_ws;
    unsigned short* Xb    = w16;                                  // 1M
    unsigned short* WqkvT = Xb    + (size_t)1024 * 1024;          // 9216*1024
    unsigned short* QKVb  = WqkvT + (size_t)QKV_N * 1024;         // 1024*9216
    unsigned short* WoT   = QKVb  + (size_t)1024 * QKV_N;         // 1M
    unsigned short* ctxb  = WoT   + (size_t)1024 * 1024;          // 4M
    unsigned short* avgb  = ctxb  + (size_t)64 * 1024 * 64;       // 1M
    float* qkvb = (float*)(avgb + (size_t)1024 * 1024);           // 9216
    float* dnf  = qkvb + QKV_N;                                   // 16*1024
    // split-K partials alias the (dead-by-then) WqkvT region: 8 MB <= 18.9 MB
    float* pWo  = (float*)WqkvT;

    dim3 blk(256);
    prep_kernel<<<3108, blk, 0, stream>>>(X, Wq, Wk, Wv, Wo, bq, bk, bv,
                                          Xb, WqkvT, WoT, qkvb);
    gemm_k<128, 96, 1><<<dim3(96, 8), blk, 0, stream>>>(Xb, WqkvT, qkvb, QKVb, 1024, QKV_N, 1024);
    rope_kernel<<<320, blk, 0, stream>>>(QKVb, dnf);
    attn_mfma<<<dim3(8, 64), dim3(512), 0, stream>>>(QKVb, dnf, sinks, vnulls, ctxb);
    avg_kernel<<<512, blk, 0, stream>>>(ctxb, avgb);
    gemm_wo<<<dim3(16, 8, 2), blk, 0, stream>>>(avgb, WoT, pWo);
    wo_reduce<<<1024, blk, 0, stream>>>(pWo, bo, out);
}

// Round 6
// 201.367 us; speedup vs baseline: 5.1032x; 1.0388x over previous
//
#include <hip/hip_runtime.h>
#include <math.h>

#define SILU_SCALE 1.8137993642342178f   // pi/sqrt(3)
#define QKV_N 9216                       // 4096 Q | 1024 K | 4096 V
#define LN2 0.6931471805599453f
#define DNSCALE 0.18033688011112042f     // 0.125 * log2(e)

typedef __attribute__((ext_vector_type(8))) short bf16x8;
typedef __attribute__((ext_vector_type(4))) float f32x4;

#if __has_builtin(__builtin_amdgcn_exp2f)
#define EXP2(x) __builtin_amdgcn_exp2f(x)
#else
#define EXP2(x) exp2f(x)
#endif
#if __has_builtin(__builtin_amdgcn_logf)
#define LOG2(x) __builtin_amdgcn_logf(x)
#else
#define LOG2(x) __log2f(x)
#endif

__device__ __forceinline__ unsigned short f2bf(float f){
    union { float f; unsigned int i; } u; u.f = f;
    unsigned int r = u.i + 0x7FFFu + ((u.i >> 16) & 1u);   // RNE
    return (unsigned short)(r >> 16);
}
__device__ __forceinline__ float bf2f(unsigned short s){
    union { unsigned int i; float f; } u; u.i = ((unsigned int)s) << 16;
    return u.f;
}
// pack two fp32 -> [hi:lo] bf16 pair, half-up rounding (1 add each + v_perm)
__device__ __forceinline__ unsigned int pack_bf2(float lo, float hi){
    unsigned int i0 = __float_as_uint(lo) + 0x8000u;
    unsigned int i1 = __float_as_uint(hi) + 0x8000u;
    return __builtin_amdgcn_perm(i1, i0, 0x07060302u);
}

// async global->LDS, 16B per lane; LDS dest = wave-uniform base + lane*16
__device__ __forceinline__ void gload_lds16(const void* g, void* l){
    __builtin_amdgcn_global_load_lds(
        (const __attribute__((address_space(1))) void*)g,
        (__attribute__((address_space(3))) void*)l, 16, 0, 0);
}

// ---------------- fused prep: 4 weight transposes (64x64 tiles) + X convert + bias ----------------
__global__ __launch_bounds__(256) void prep_kernel(
    const float* __restrict__ X,
    const float* __restrict__ Wq, const float* __restrict__ Wk,
    const float* __restrict__ Wv, const float* __restrict__ Wo,
    const float* __restrict__ bq, const float* __restrict__ bk,
    const float* __restrict__ bv,
    unsigned short* __restrict__ Xb, unsigned short* __restrict__ WqkvT,
    unsigned short* __restrict__ WoT, float* __restrict__ qkvb)
{
    __shared__ float t[64][65];
    int b = blockIdx.x;
    const int tid = threadIdx.x;

    if (b >= 2560){
        if (b < 3072){   // X fp32 -> bf16, 8/thread
            int i = ((b - 2560) * 256 + tid) * 8;
            float4 a = *(const float4*)&X[i];
            float4 c = *(const float4*)&X[i + 4];
            union { unsigned short u[8]; uint4 v; } o;
            o.u[0]=f2bf(a.x); o.u[1]=f2bf(a.y); o.u[2]=f2bf(a.z); o.u[3]=f2bf(a.w);
            o.u[4]=f2bf(c.x); o.u[5]=f2bf(c.y); o.u[6]=f2bf(c.z); o.u[7]=f2bf(c.w);
            *(uint4*)&Xb[i] = o.v;
        } else {          // bias pack
            int i = (b - 3072) * 256 + tid;
            float v;
            if (i < 4096) v = bq[i];
            else if (i < 5120) v = bk[i - 4096];
            else v = bv[i - 5120];
            qkvb[i] = v;
        }
        return;
    }

    const float* W; unsigned short* Wt; int N, tiles_x;
    if (b < 1024)      { W = Wq; Wt = WqkvT;                       N = 4096; tiles_x = 64; }
    else if (b < 1280) { b -= 1024; W = Wk; Wt = WqkvT + (size_t)4096*1024; N = 1024; tiles_x = 16; }
    else if (b < 2304) { b -= 1280; W = Wv; Wt = WqkvT + (size_t)5120*1024; N = 4096; tiles_x = 64; }
    else               { b -= 2304; W = Wo; Wt = WoT;              N = 1024; tiles_x = 16; }

    const int k0 = (b / tiles_x) * 64, n0 = (b % tiles_x) * 64;
    const int lr  = tid >> 4;          // 0..15
    const int lc4 = (tid & 15) * 4;    // 0..60
    #pragma unroll
    for (int p = 0; p < 4; p++){
        int r = lr + p * 16;
        float4 v = *(const float4*)&W[(size_t)(k0 + r) * N + n0 + lc4];
        t[lc4+0][r] = v.x; t[lc4+1][r] = v.y;
        t[lc4+2][r] = v.z; t[lc4+3][r] = v.w;
    }
    __syncthreads();
    const int wr  = tid >> 3;          // 0..31
    const int wc8 = (tid & 7) * 8;     // 0..56
    #pragma unroll
    for (int p = 0; p < 2; p++){
        int r = wr + p * 32;
        union { unsigned short u[8]; uint4 v; } o;
        #pragma unroll
        for (int j = 0; j < 8; j++) o.u[j] = f2bf(t[r][wc8 + j]);
        *(uint4*)&Wt[(size_t)(n0 + r) * 1024 + k0 + wc8] = o.v;
    }
}

// ---------------- bf16 MFMA GEMM (m97-style): C = A[M,K] @ Bt[N,K]^T + bias ----------------
template<int BM, int BN, int OUTBF>
__global__ __launch_bounds__(256) void gemm_k(
    const unsigned short* __restrict__ A,
    const unsigned short* __restrict__ Bt,
    const float* __restrict__ bias,
    void* __restrict__ Cout, int M, int N, int K)
{
    constexpr int MT = BM / 32;
    constexpr int NT = BN / 32;
    __shared__ unsigned short As[BM * 64];
    __shared__ unsigned short Bs[BN * 64];
    const int tid  = threadIdx.x;
    const int wave = tid >> 6;
    const int lane = tid & 63;
    const int l15  = lane & 15;
    const int quad = lane >> 4;
    const int m0 = blockIdx.y * BM;
    const int n0 = blockIdx.x * BN;
    const int wm = (wave >> 1) * (BM / 2);
    const int wn = (wave & 1) * (BN / 2);

    f32x4 acc[MT][NT];
    #pragma unroll
    for (int i = 0; i < MT; i++)
        #pragma unroll
        for (int j = 0; j < NT; j++)
            acc[i][j] = (f32x4){0.f, 0.f, 0.f, 0.f};

    for (int k0 = 0; k0 < K; k0 += 64){
        #pragma unroll
        for (int j = 0; j < (BM * 8) / 256; j++){
            int bslot = j * 256 + wave * 64;
            int slot = bslot + lane;
            int row = slot >> 3, phys = slot & 7;
            int c = phys ^ (row & 7);
            gload_lds16(&A[(size_t)(m0 + row) * K + k0 + c * 8], &As[bslot * 8]);
        }
        #pragma unroll
        for (int j = 0; j < (BN * 8) / 256; j++){
            int bslot = j * 256 + wave * 64;
            int slot = bslot + lane;
            int row = slot >> 3, phys = slot & 7;
            int c = phys ^ (row & 7);
            gload_lds16(&Bt[(size_t)(n0 + row) * K + k0 + c * 8], &Bs[bslot * 8]);
        }
        __syncthreads();
        #pragma unroll
        for (int ks = 0; ks < 2; ks++){
            bf16x8 af[MT], bfr[NT];
            #pragma unroll
            for (int i = 0; i < MT; i++){
                int row = wm + i * 16 + l15;
                int phys = (ks * 4 + quad) ^ (row & 7);
                af[i] = *(const bf16x8*)&As[row * 64 + phys * 8];
            }
            #pragma unroll
            for (int j = 0; j < NT; j++){
                int row = wn + j * 16 + l15;
                int phys = (ks * 4 + quad) ^ (row & 7);
                bfr[j] = *(const bf16x8*)&Bs[row * 64 + phys * 8];
            }
            #pragma unroll
            for (int i = 0; i < MT; i++)
                #pragma unroll
                for (int j = 0; j < NT; j++)
                    acc[i][j] = __builtin_amdgcn_mfma_f32_16x16x32_bf16(af[i], bfr[j], acc[i][j], 0, 0, 0);
        }
        __syncthreads();
    }
    #pragma unroll
    for (int i = 0; i < MT; i++){
        #pragma unroll
        for (int j = 0; j < NT; j++){
            int col = n0 + wn + j * 16 + l15;
            float bv = bias[col];
            #pragma unroll
            for (int r = 0; r < 4; r++){
                int row = m0 + wm + i * 16 + quad * 4 + r;
                float v = acc[i][j][r] + bv;
                if (OUTBF) ((unsigned short*)Cout)[(size_t)row * N + col] = f2bf(v);
                else       ((float*)Cout)[(size_t)row * N + col] = v;
            }
        }
    }
}

// ---------------- Wo GEMM, split-K=2 ----------------
__global__ __launch_bounds__(256) void gemm_wo(
    const unsigned short* __restrict__ A,    // avgb [1024][1024] bf16
    const unsigned short* __restrict__ Bt,   // WoT  [1024][1024] bf16
    float* __restrict__ P)                   // [2][1024][1024] fp32 partials
{
    constexpr int BM = 128, BN = 64, MT = 4, NT = 2;
    __shared__ unsigned short As[BM * 64];
    __shared__ unsigned short Bs[BN * 64];
    const int tid  = threadIdx.x;
    const int wave = tid >> 6;
    const int lane = tid & 63;
    const int l15  = lane & 15;
    const int quad = lane >> 4;
    const int m0 = blockIdx.y * BM;
    const int n0 = blockIdx.x * BN;
    const int kz = blockIdx.z;
    const int wm = (wave >> 1) * 64;
    const int wn = (wave & 1) * 32;

    f32x4 acc[MT][NT];
    #pragma unroll
    for (int i = 0; i < MT; i++)
        #pragma unroll
        for (int j = 0; j < NT; j++)
            acc[i][j] = (f32x4){0.f, 0.f, 0.f, 0.f};

    const int kbeg = kz * 512;
    for (int k0 = kbeg; k0 < kbeg + 512; k0 += 64){
        #pragma unroll
        for (int j = 0; j < (BM * 8) / 256; j++){
            int bslot = j * 256 + wave * 64;
            int slot = bslot + lane;
            int row = slot >> 3, phys = slot & 7;
            int c = phys ^ (row & 7);
            gload_lds16(&A[(size_t)(m0 + row) * 1024 + k0 + c * 8], &As[bslot * 8]);
        }
        #pragma unroll
        for (int j = 0; j < (BN * 8) / 256; j++){
            int bslot = j * 256 + wave * 64;
            int slot = bslot + lane;
            int row = slot >> 3, phys = slot & 7;
            int c = phys ^ (row & 7);
            gload_lds16(&Bt[(size_t)(n0 + row) * 1024 + k0 + c * 8], &Bs[bslot * 8]);
        }
        __syncthreads();
        #pragma unroll
        for (int ks = 0; ks < 2; ks++){
            bf16x8 af[MT], bfr[NT];
            #pragma unroll
            for (int i = 0; i < MT; i++){
                int row = wm + i * 16 + l15;
                int phys = (ks * 4 + quad) ^ (row & 7);
                af[i] = *(const bf16x8*)&As[row * 64 + phys * 8];
            }
            #pragma unroll
            for (int j = 0; j < NT; j++){
                int row = wn + j * 16 + l15;
                int phys = (ks * 4 + quad) ^ (row & 7);
                bfr[j] = *(const bf16x8*)&Bs[row * 64 + phys * 8];
            }
            #pragma unroll
            for (int i = 0; i < MT; i++)
                #pragma unroll
                for (int j = 0; j < NT; j++)
                    acc[i][j] = __builtin_amdgcn_mfma_f32_16x16x32_bf16(af[i], bfr[j], acc[i][j], 0, 0, 0);
        }
        __syncthreads();
    }
    float* Pz = P + (size_t)kz * 1024 * 1024;
    #pragma unroll
    for (int i = 0; i < MT; i++){
        #pragma unroll
        for (int j = 0; j < NT; j++){
            int col = n0 + wn + j * 16 + l15;
            #pragma unroll
            for (int r = 0; r < 4; r++){
                int row = m0 + wm + i * 16 + quad * 4 + r;
                Pz[(size_t)row * 1024 + col] = acc[i][j][r];
            }
        }
    }
}

// out = P[0] + P[1] + bias  (fp32, 4/thread)
__global__ void wo_reduce(const float* __restrict__ P, const float* __restrict__ bo,
                          float* __restrict__ out)
{
    int i = (blockIdx.x * 256 + threadIdx.x) * 4;   // 1M floats
    float4 a = *(const float4*)&P[i];
    float4 b = *(const float4*)&P[1024 * 1024 + i];
    float4 c = *(const float4*)&bo[i & 1023];
    float4 o;
    o.x = a.x + b.x + c.x; o.y = a.y + b.y + c.y;
    o.z = a.z + b.z + c.z; o.w = a.w + b.w + c.w;
    *(float4*)&out[i] = o;
}

// ---------------- RoPE on K only + per-key norm (Q-rope is fused into attn) ----------------
__global__ void rope_k(unsigned short* __restrict__ qkv, float* __restrict__ dninv)
{
    int idx = blockIdx.x * blockDim.x + threadIdx.x;   // 16384: (t, kh 0..15)
    int t = idx >> 4, h = idx & 15;
    unsigned short* p = qkv + (size_t)t * QKV_N + 4096 + h * 64;
    uint4 raw[8];
    #pragma unroll
    for (int i = 0; i < 8; i++) raw[i] = *(const uint4*)(p + i * 8);
    const unsigned short* rp = (const unsigned short*)raw;
    float x[64];
    #pragma unroll
    for (int i = 0; i < 64; i++) x[i] = bf2f(rp[i]);
    unsigned short o[64];
    float ss = 0.f;
    #pragma unroll
    for (int d = 0; d < 32; d++){
        float inv = EXP2(-(float)d * 0.4152410118609203f);   // log2(1e4)/32
        float s, c; __sincosf((float)t * inv, &s, &c);
        float x1 = x[2*d], x2 = x[2*d+1];
        float a = x1 * c - x2 * s;
        float b = x1 * s + x2 * c;
        ss = fmaf(a, a, fmaf(b, b, ss));
        o[d]      = f2bf(a);
        o[d + 32] = f2bf(b);
    }
    #pragma unroll
    for (int i = 0; i < 8; i++) *(uint4*)(p + i * 8) = ((const uint4*)o)[i];
    dninv[h * 1024 + t] = DNSCALE * rsqrtf(fmaxf(ss, 1e-6f));
}

// ---------------- fused attention ----------------
// grid (h 0..63, qy 0..15), qt = 15 - qy (longest blocks dispatch first).
// 256 thr = 4 waves; wave w owns q rows [w*16, w*16+16). Q-RoPE fused at fragment load.
__global__ __launch_bounds__(256) void attn_mfma(
    const unsigned short* __restrict__ qkv,
    const float* __restrict__ dninv,
    const float* __restrict__ sinks, const float* __restrict__ vnulls,
    unsigned short* __restrict__ ctx)       // [64][1024][64] bf16
{
    __shared__ unsigned short ks[64 * 64];          // [s][chunk ^ (s&7)]
    __shared__ unsigned short vt[64 * 64];          // [d][chunk ^ ((d^(d>>3))&7)]
    __shared__ unsigned short ws[64][72];           // P [q][s]
    __shared__ float dl[64];
    __shared__ float dsum[4][16];

    const int tid  = threadIdx.x;
    const int wave = tid >> 6;          // 0..3
    const int lane = tid & 63;
    const int l15  = lane & 15;
    const int quad = lane >> 4;
    const int h  = blockIdx.x;
    const int kh = h & 15;
    const int qt = 15 - blockIdx.y;
    const int t0 = qt << 6;

    const unsigned short* Q  = qkv;
    const unsigned short* Kp = qkv + 4096;
    const unsigned short* V  = qkv + 5120;

    // Q fragment with fused RoPE (Q in global is un-roped).
    // Output frag d in [quad*8, +8) and [quad*8+32, +8) needs inputs [quad*16, +16).
    bf16x8 qf0, qf1;
    {
        const int t = t0 + wave * 16 + l15;
        const unsigned short* qp = Q + (size_t)t * QKV_N + h * 64 + quad * 16;
        uint4 r0 = *(const uint4*)qp;
        uint4 r1 = *(const uint4*)(qp + 8);
        unsigned short e[16];
        *(uint4*)&e[0] = r0; *(uint4*)&e[8] = r1;
        unsigned short o0[8], o1[8];
        #pragma unroll
        for (int j = 0; j < 8; j++){
            int dp = quad * 8 + j;
            float inv = EXP2(-(float)dp * 0.4152410118609203f);
            float s, c; __sincosf((float)t * inv, &s, &c);
            float x1 = bf2f(e[2*j]), x2 = bf2f(e[2*j+1]);
            o0[j] = f2bf(x1 * c - x2 * s);
            o1[j] = f2bf(x1 * s + x2 * c);
        }
        qf0 = *(const bf16x8*)o0;
        qf1 = *(const bf16x8*)o1;
    }

    f32x4 acc_o[4];
    #pragma unroll
    for (int i = 0; i < 4; i++) acc_o[i] = (f32x4){0.f, 0.f, 0.f, 0.f};
    float den = 0.f;                    // per-lane, q = wave*16 + l15
    const int q_glob = t0 + wave * 16 + l15;

    const int pr  = tid >> 3;           // 0..31 (V staging)
    const int cch = tid & 7;

    for (int st = 0; st <= qt; st++){
        const int s0 = st << 6;
        __syncthreads();                // previous iteration's LDS reads done

        // K tile: 2 async global_load_lds per wave (4 waves cover 64 rows x 8 chunks)
        #pragma unroll
        for (int i = 0; i < 2; i++){
            int bslot = wave * 128 + i * 64;
            int slot = bslot + lane;
            int row = slot >> 3, phys = slot & 7;
            int c = phys ^ (row & 7);
            gload_lds16(&Kp[(size_t)(s0 + row) * QKV_N + kh * 64 + c * 8], &ks[bslot * 8]);
        }
        {   // V tile transposed, packed-pair b32 writes (all 256 threads)
            uint4 g0 = *(const uint4*)&V[(size_t)(s0 + 2 * pr)     * QKV_N + h * 64 + cch * 8];
            uint4 g1 = *(const uint4*)&V[(size_t)(s0 + 2 * pr + 1) * QKV_N + h * 64 + cch * 8];
            const unsigned short* p0 = (const unsigned short*)&g0;
            const unsigned short* p1 = (const unsigned short*)&g1;
            #pragma unroll
            for (int j = 0; j < 8; j++){
                int d = cch * 8 + j;
                int physc = (pr >> 2) ^ ((d ^ (d >> 3)) & 7);
                unsigned int val = (unsigned int)p0[j] | ((unsigned int)p1[j] << 16);
                ((unsigned int*)vt)[d * 32 + physc * 4 + (pr & 3)] = val;
            }
        }
        if (tid < 64) dl[tid] = dninv[kh * 1024 + s0 + tid];
        __syncthreads();

        const bool diag = (st == qt);

        // S^T: mfma(kf, qf) -> lane owns 4 consecutive s (quad*4+r) for q = l15
        #pragma unroll
        for (int nt = 0; nt < 4; nt++){
            const int sbase = nt * 16 + quad * 4;
            uint2* wp = (uint2*)&ws[wave * 16 + l15][sbase];
            if (diag && nt > wave){ *wp = (uint2){0u, 0u}; continue; }

            f32x4 sc = (f32x4){0.f, 0.f, 0.f, 0.f};
            {
                int srow = nt * 16 + l15;
                int ph0 = quad ^ (srow & 7);
                int ph1 = (4 + quad) ^ (srow & 7);
                bf16x8 kf0 = *(const bf16x8*)&ks[srow * 64 + ph0 * 8];
                bf16x8 kf1 = *(const bf16x8*)&ks[srow * 64 + ph1 * 8];
                sc = __builtin_amdgcn_mfma_f32_16x16x32_bf16(kf0, qf0, sc, 0, 0, 0);
                sc = __builtin_amdgcn_mfma_f32_16x16x32_bf16(kf1, qf1, sc, 0, 0, 0);
            }
            float da[4];
            *(float4*)da = *(const float4*)&dl[sbase];
            float w4[4];
            #pragma unroll
            for (int r = 0; r < 4; r++){
                float y = sc[r] * da[r];                      // x * log2(e)
                float p = EXP2(-fabsf(y));
                float u = fmaxf(y, 0.f) + LOG2(1.f + p);      // softplus * log2(e)
                float e3 = EXP2(-SILU_SCALE * u);             // == exp(-SCALE*softplus)
                float wv = __fdividef(LN2 * u, 1.f + e3);
                wv = (s0 + sbase + r <= q_glob) ? wv : 0.f;
                den += wv;
                w4[r] = wv;
            }
            uint2 pk;
            pk.x = pack_bf2(w4[0], w4[1]);
            pk.y = pack_bf2(w4[2], w4[3]);
            *wp = pk;
        }

        // PV (wave-private ws rows)
        {
            const int prow = wave * 16 + l15;
            bf16x8 pf0 = *(const bf16x8*)&ws[prow][quad * 8];
            bf16x8 pf1 = *(const bf16x8*)&ws[prow][32 + quad * 8];
            const bool skip_hi = diag && (wave <= 1);   // s>=32 all masked
            #pragma unroll
            for (int dt = 0; dt < 4; dt++){
                int d = dt * 16 + l15;
                int swz = (d ^ (d >> 3)) & 7;
                bf16x8 vf0 = *(const bf16x8*)&vt[d * 64 + (quad ^ swz) * 8];
                acc_o[dt] = __builtin_amdgcn_mfma_f32_16x16x32_bf16(pf0, vf0, acc_o[dt], 0, 0, 0);
                if (!skip_hi){
                    bf16x8 vf1 = *(const bf16x8*)&vt[d * 64 + ((4 + quad) ^ swz) * 8];
                    acc_o[dt] = __builtin_amdgcn_mfma_f32_16x16x32_bf16(pf1, vf1, acc_o[dt], 0, 0, 0);
                }
            }
        }
    }

    // denominator: reduce across quads (same q = l15), redistribute via LDS
    den += __shfl_xor(den, 16);
    den += __shfl_xor(den, 32);
    if (quad == 0) dsum[wave][l15] = den;
    float den4[4];
    *(float4*)den4 = *(const float4*)&dsum[wave][quad * 4];

    float sinkv = tanhf(sinks[h]) + 1e-6f;
    #pragma unroll
    for (int r = 0; r < 4; r++){
        int qg = t0 + wave * 16 + quad * 4 + r;
        float alpha = __fdividef(1.f, den4[r] + sinkv + 1e-6f);
        #pragma unroll
        for (int dt = 0; dt < 4; dt++){
            int d = dt * 16 + l15;
            float o = (acc_o[dt][r] + sinkv * vnulls[h * 64 + d]) * alpha;
            ctx[((size_t)h * 1024 + qg) * 64 + d] = f2bf(o);
        }
    }
}

// avg over 4 branches -> bf16 [t][nh*64+d], 8 elems/thread
__global__ void avg_kernel(const unsigned short* __restrict__ ctx, unsigned short* __restrict__ avg)
{
    int i8 = (blockIdx.x * 256 + threadIdx.x) * 8;   // 1M elements
    int t = i8 >> 10, c = i8 & 1023;
    int nh = c >> 6, d = c & 63;
    float s[8] = {};
    #pragma unroll
    for (int br = 0; br < 4; br++){
        uint4 v = *(const uint4*)&ctx[((size_t)(br * 16 + nh) * 1024 + t) * 64 + d];
        const unsigned short* p = (const unsigned short*)&v;
        #pragma unroll
        for (int j = 0; j < 8; j++) s[j] += bf2f(p[j]);
    }
    union { unsigned short u[8]; uint4 v; } o;
    #pragma unroll
    for (int j = 0; j < 8; j++) o.u[j] = f2bf(0.25f * s[j]);
    *(uint4*)&avg[i8] = o.v;
}

extern "C" void kernel_launch(void* const* d_in, const int* in_sizes, int n_in,
                              void* d_out, int out_size, void* d_ws, size_t ws_size,
                              hipStream_t stream)
{
    (void)in_sizes; (void)n_in; (void)out_size; (void)ws_size;
    const float* X      = (const float*)d_in[0];
    const float* Wq     = (const float*)d_in[1];
    const float* bq     = (const float*)d_in[2];
    const float* Wk     = (const float*)d_in[3];
    const float* bk     = (const float*)d_in[4];
    const float* Wv     = (const float*)d_in[5];
    const float* bv     = (const float*)d_in[6];
    const float* sinks  = (const float*)d_in[7];
    const float* vnulls = (const float*)d_in[8];
    const float* Wo     = (const float*)d_in[9];
    const float* bo     = (const float*)d_in[10];
    float* out = (float*)d_out;

    unsigned short* w16   = (unsigned short*)d_ws;
    unsigned short* Xb    = w16;                                  // 1M
    unsigned short* WqkvT = Xb    + (size_t)1024 * 1024;          // 9216*1024
    unsigned short* QKVb  = WqkvT + (size_t)QKV_N * 1024;         // 1024*9216
    unsigned short* WoT   = QKVb  + (size_t)1024 * QKV_N;         // 1M
    unsigned short* ctxb  = WoT   + (size_t)1024 * 1024;          // 4M
    unsigned short* avgb  = ctxb  + (size_t)64 * 1024 * 64;       // 1M
    float* qkvb = (float*)(avgb + (size_t)1024 * 1024);           // 9216
    float* dnf  = qkvb + QKV_N;                                   // 16*1024
    // split-K partials alias the (dead-by-then) WqkvT region: 8 MB <= 18.9 MB
    float* pWo  = (float*)WqkvT;

    dim3 blk(256);
    prep_kernel<<<3108, blk, 0, stream>>>(X, Wq, Wk, Wv, Wo, bq, bk, bv,
                                          Xb, WqkvT, WoT, qkvb);
    gemm_k<128, 96, 1><<<dim3(96, 8), blk, 0, stream>>>(Xb, WqkvT, qkvb, QKVb, 1024, QKV_N, 1024);
    rope_k<<<64, blk, 0, stream>>>(QKVb, dnf);
    attn_mfma<<<dim3(64, 16), blk, 0, stream>>>(QKVb, dnf, sinks, vnulls, ctxb);
    avg_kernel<<<512, blk, 0, stream>>>(ctxb, avgb);
    gemm_wo<<<dim3(16, 8, 2), blk, 0, stream>>>(avgb, WoT, pWo);
    wo_reduce<<<1024, blk, 0, stream>>>(pWo, bo, out);
}

// Round 7
// 192.396 us; speedup vs baseline: 5.3412x; 1.0466x over previous
//
#include <hip/hip_runtime.h>
#include <math.h>

#define SILU_SCALE 1.8137993642342178f   // pi/sqrt(3)
#define QKV_N 9216                       // 4096 Q | 1024 K | 4096 V
#define LN2 0.6931471805599453f
#define DNSCALE 0.18033688011112042f     // 0.125 * log2(e)

typedef __attribute__((ext_vector_type(8))) short bf16x8;
typedef __attribute__((ext_vector_type(4))) float f32x4;

#if __has_builtin(__builtin_amdgcn_exp2f)
#define EXP2(x) __builtin_amdgcn_exp2f(x)
#else
#define EXP2(x) exp2f(x)
#endif
#if __has_builtin(__builtin_amdgcn_logf)
#define LOG2(x) __builtin_amdgcn_logf(x)
#else
#define LOG2(x) __log2f(x)
#endif

__device__ __forceinline__ unsigned short f2bf(float f){
    union { float f; unsigned int i; } u; u.f = f;
    unsigned int r = u.i + 0x7FFFu + ((u.i >> 16) & 1u);   // RNE
    return (unsigned short)(r >> 16);
}
__device__ __forceinline__ float bf2f(unsigned short s){
    union { unsigned int i; float f; } u; u.i = ((unsigned int)s) << 16;
    return u.f;
}
// pack two fp32 -> [hi:lo] bf16 pair, half-up rounding (1 add each + v_perm)
__device__ __forceinline__ unsigned int pack_bf2(float lo, float hi){
    unsigned int i0 = __float_as_uint(lo) + 0x8000u;
    unsigned int i1 = __float_as_uint(hi) + 0x8000u;
    return __builtin_amdgcn_perm(i1, i0, 0x07060302u);
}

// async global->LDS, 16B per lane; LDS dest = wave-uniform base + lane*16
__device__ __forceinline__ void gload_lds16(const void* g, void* l){
    __builtin_amdgcn_global_load_lds(
        (const __attribute__((address_space(1))) void*)g,
        (__attribute__((address_space(3))) void*)l, 16, 0, 0);
}

// ---------------- fused prep: 4 weight transposes (64x64 tiles) + X convert + bias ----------------
__global__ __launch_bounds__(256) void prep_kernel(
    const float* __restrict__ X,
    const float* __restrict__ Wq, const float* __restrict__ Wk,
    const float* __restrict__ Wv, const float* __restrict__ Wo,
    const float* __restrict__ bq, const float* __restrict__ bk,
    const float* __restrict__ bv,
    unsigned short* __restrict__ Xb, unsigned short* __restrict__ WqkvT,
    unsigned short* __restrict__ WoT, float* __restrict__ qkvb)
{
    __shared__ float t[64][65];
    int b = blockIdx.x;
    const int tid = threadIdx.x;

    if (b >= 2560){
        if (b < 3072){   // X fp32 -> bf16, 8/thread
            int i = ((b - 2560) * 256 + tid) * 8;
            float4 a = *(const float4*)&X[i];
            float4 c = *(const float4*)&X[i + 4];
            union { unsigned short u[8]; uint4 v; } o;
            o.u[0]=f2bf(a.x); o.u[1]=f2bf(a.y); o.u[2]=f2bf(a.z); o.u[3]=f2bf(a.w);
            o.u[4]=f2bf(c.x); o.u[5]=f2bf(c.y); o.u[6]=f2bf(c.z); o.u[7]=f2bf(c.w);
            *(uint4*)&Xb[i] = o.v;
        } else {          // bias pack
            int i = (b - 3072) * 256 + tid;
            float v;
            if (i < 4096) v = bq[i];
            else if (i < 5120) v = bk[i - 4096];
            else v = bv[i - 5120];
            qkvb[i] = v;
        }
        return;
    }

    const float* W; unsigned short* Wt; int N, tiles_x;
    if (b < 1024)      { W = Wq; Wt = WqkvT;                       N = 4096; tiles_x = 64; }
    else if (b < 1280) { b -= 1024; W = Wk; Wt = WqkvT + (size_t)4096*1024; N = 1024; tiles_x = 16; }
    else if (b < 2304) { b -= 1280; W = Wv; Wt = WqkvT + (size_t)5120*1024; N = 4096; tiles_x = 64; }
    else               { b -= 2304; W = Wo; Wt = WoT;              N = 1024; tiles_x = 16; }

    const int k0 = (b / tiles_x) * 64, n0 = (b % tiles_x) * 64;
    const int lr  = tid >> 4;          // 0..15
    const int lc4 = (tid & 15) * 4;    // 0..60
    #pragma unroll
    for (int p = 0; p < 4; p++){
        int r = lr + p * 16;
        float4 v = *(const float4*)&W[(size_t)(k0 + r) * N + n0 + lc4];
        t[lc4+0][r] = v.x; t[lc4+1][r] = v.y;
        t[lc4+2][r] = v.z; t[lc4+3][r] = v.w;
    }
    __syncthreads();
    const int wr  = tid >> 3;          // 0..31
    const int wc8 = (tid & 7) * 8;     // 0..56
    #pragma unroll
    for (int p = 0; p < 2; p++){
        int r = wr + p * 32;
        union { unsigned short u[8]; uint4 v; } o;
        #pragma unroll
        for (int j = 0; j < 8; j++) o.u[j] = f2bf(t[r][wc8 + j]);
        *(uint4*)&Wt[(size_t)(n0 + r) * 1024 + k0 + wc8] = o.v;
    }
}

// ---------------- bf16 MFMA GEMM (m97-style): C = A[M,K] @ Bt[N,K]^T + bias ----------------
template<int BM, int BN, int OUTBF>
__global__ __launch_bounds__(256) void gemm_k(
    const unsigned short* __restrict__ A,
    const unsigned short* __restrict__ Bt,
    const float* __restrict__ bias,
    void* __restrict__ Cout, int M, int N, int K)
{
    constexpr int MT = BM / 32;
    constexpr int NT = BN / 32;
    __shared__ unsigned short As[BM * 64];
    __shared__ unsigned short Bs[BN * 64];
    const int tid  = threadIdx.x;
    const int wave = tid >> 6;
    const int lane = tid & 63;
    const int l15  = lane & 15;
    const int quad = lane >> 4;
    const int m0 = blockIdx.y * BM;
    const int n0 = blockIdx.x * BN;
    const int wm = (wave >> 1) * (BM / 2);
    const int wn = (wave & 1) * (BN / 2);

    f32x4 acc[MT][NT];
    #pragma unroll
    for (int i = 0; i < MT; i++)
        #pragma unroll
        for (int j = 0; j < NT; j++)
            acc[i][j] = (f32x4){0.f, 0.f, 0.f, 0.f};

    for (int k0 = 0; k0 < K; k0 += 64){
        #pragma unroll
        for (int j = 0; j < (BM * 8) / 256; j++){
            int bslot = j * 256 + wave * 64;
            int slot = bslot + lane;
            int row = slot >> 3, phys = slot & 7;
            int c = phys ^ (row & 7);
            gload_lds16(&A[(size_t)(m0 + row) * K + k0 + c * 8], &As[bslot * 8]);
        }
        #pragma unroll
        for (int j = 0; j < (BN * 8) / 256; j++){
            int bslot = j * 256 + wave * 64;
            int slot = bslot + lane;
            int row = slot >> 3, phys = slot & 7;
            int c = phys ^ (row & 7);
            gload_lds16(&Bt[(size_t)(n0 + row) * K + k0 + c * 8], &Bs[bslot * 8]);
        }
        __syncthreads();
        #pragma unroll
        for (int ks = 0; ks < 2; ks++){
            bf16x8 af[MT], bfr[NT];
            #pragma unroll
            for (int i = 0; i < MT; i++){
                int row = wm + i * 16 + l15;
                int phys = (ks * 4 + quad) ^ (row & 7);
                af[i] = *(const bf16x8*)&As[row * 64 + phys * 8];
            }
            #pragma unroll
            for (int j = 0; j < NT; j++){
                int row = wn + j * 16 + l15;
                int phys = (ks * 4 + quad) ^ (row & 7);
                bfr[j] = *(const bf16x8*)&Bs[row * 64 + phys * 8];
            }
            #pragma unroll
            for (int i = 0; i < MT; i++)
                #pragma unroll
                for (int j = 0; j < NT; j++)
                    acc[i][j] = __builtin_amdgcn_mfma_f32_16x16x32_bf16(af[i], bfr[j], acc[i][j], 0, 0, 0);
        }
        __syncthreads();
    }
    #pragma unroll
    for (int i = 0; i < MT; i++){
        #pragma unroll
        for (int j = 0; j < NT; j++){
            int col = n0 + wn + j * 16 + l15;
            float bv = bias[col];
            #pragma unroll
            for (int r = 0; r < 4; r++){
                int row = m0 + wm + i * 16 + quad * 4 + r;
                float v = acc[i][j][r] + bv;
                if (OUTBF) ((unsigned short*)Cout)[(size_t)row * N + col] = f2bf(v);
                else       ((float*)Cout)[(size_t)row * N + col] = v;
            }
        }
    }
}

// ---------------- Wo GEMM, split-K=2 ----------------
__global__ __launch_bounds__(256) void gemm_wo(
    const unsigned short* __restrict__ A,    // avgb [1024][1024] bf16
    const unsigned short* __restrict__ Bt,   // WoT  [1024][1024] bf16
    float* __restrict__ P)                   // [2][1024][1024] fp32 partials
{
    constexpr int BM = 128, BN = 64, MT = 4, NT = 2;
    __shared__ unsigned short As[BM * 64];
    __shared__ unsigned short Bs[BN * 64];
    const int tid  = threadIdx.x;
    const int wave = tid >> 6;
    const int lane = tid & 63;
    const int l15  = lane & 15;
    const int quad = lane >> 4;
    const int m0 = blockIdx.y * BM;
    const int n0 = blockIdx.x * BN;
    const int kz = blockIdx.z;
    const int wm = (wave >> 1) * 64;
    const int wn = (wave & 1) * 32;

    f32x4 acc[MT][NT];
    #pragma unroll
    for (int i = 0; i < MT; i++)
        #pragma unroll
        for (int j = 0; j < NT; j++)
            acc[i][j] = (f32x4){0.f, 0.f, 0.f, 0.f};

    const int kbeg = kz * 512;
    for (int k0 = kbeg; k0 < kbeg + 512; k0 += 64){
        #pragma unroll
        for (int j = 0; j < (BM * 8) / 256; j++){
            int bslot = j * 256 + wave * 64;
            int slot = bslot + lane;
            int row = slot >> 3, phys = slot & 7;
            int c = phys ^ (row & 7);
            gload_lds16(&A[(size_t)(m0 + row) * 1024 + k0 + c * 8], &As[bslot * 8]);
        }
        #pragma unroll
        for (int j = 0; j < (BN * 8) / 256; j++){
            int bslot = j * 256 + wave * 64;
            int slot = bslot + lane;
            int row = slot >> 3, phys = slot & 7;
            int c = phys ^ (row & 7);
            gload_lds16(&Bt[(size_t)(n0 + row) * 1024 + k0 + c * 8], &Bs[bslot * 8]);
        }
        __syncthreads();
        #pragma unroll
        for (int ks = 0; ks < 2; ks++){
            bf16x8 af[MT], bfr[NT];
            #pragma unroll
            for (int i = 0; i < MT; i++){
                int row = wm + i * 16 + l15;
                int phys = (ks * 4 + quad) ^ (row & 7);
                af[i] = *(const bf16x8*)&As[row * 64 + phys * 8];
            }
            #pragma unroll
            for (int j = 0; j < NT; j++){
                int row = wn + j * 16 + l15;
                int phys = (ks * 4 + quad) ^ (row & 7);
                bfr[j] = *(const bf16x8*)&Bs[row * 64 + phys * 8];
            }
            #pragma unroll
            for (int i = 0; i < MT; i++)
                #pragma unroll
                for (int j = 0; j < NT; j++)
                    acc[i][j] = __builtin_amdgcn_mfma_f32_16x16x32_bf16(af[i], bfr[j], acc[i][j], 0, 0, 0);
        }
        __syncthreads();
    }
    float* Pz = P + (size_t)kz * 1024 * 1024;
    #pragma unroll
    for (int i = 0; i < MT; i++){
        #pragma unroll
        for (int j = 0; j < NT; j++){
            int col = n0 + wn + j * 16 + l15;
            #pragma unroll
            for (int r = 0; r < 4; r++){
                int row = m0 + wm + i * 16 + quad * 4 + r;
                Pz[(size_t)row * 1024 + col] = acc[i][j][r];
            }
        }
    }
}

// out = P[0] + P[1] + bias  (fp32, 4/thread)
__global__ void wo_reduce(const float* __restrict__ P, const float* __restrict__ bo,
                          float* __restrict__ out)
{
    int i = (blockIdx.x * 256 + threadIdx.x) * 4;   // 1M floats
    float4 a = *(const float4*)&P[i];
    float4 b = *(const float4*)&P[1024 * 1024 + i];
    float4 c = *(const float4*)&bo[i & 1023];
    float4 o;
    o.x = a.x + b.x + c.x; o.y = a.y + b.y + c.y;
    o.z = a.z + b.z + c.z; o.w = a.w + b.w + c.w;
    *(float4*)&out[i] = o;
}

// ---------------- postproc: RoPE on K (+norm) AND V pre-transpose VT[h][d][t] ----------------
// blocks [0,64): rope_k (one thread per (t,kh)); blocks [64,1088): V transpose tiles
__global__ __launch_bounds__(256) void postproc_kernel(
    unsigned short* __restrict__ qkv, float* __restrict__ dninv,
    unsigned short* __restrict__ VT)
{
    int b = blockIdx.x;
    const int tid = threadIdx.x;
    if (b < 64){
        int idx = b * 256 + tid;     // 16384: (t, kh 0..15)
        int t = idx >> 4, h = idx & 15;
        unsigned short* p = qkv + (size_t)t * QKV_N + 4096 + h * 64;
        uint4 raw[8];
        #pragma unroll
        for (int i = 0; i < 8; i++) raw[i] = *(const uint4*)(p + i * 8);
        const unsigned short* rp = (const unsigned short*)raw;
        float x[64];
        #pragma unroll
        for (int i = 0; i < 64; i++) x[i] = bf2f(rp[i]);
        unsigned short o[64];
        float ss = 0.f;
        #pragma unroll
        for (int d = 0; d < 32; d++){
            float inv = EXP2(-(float)d * 0.4152410118609203f);   // log2(1e4)/32
            float s, c; __sincosf((float)t * inv, &s, &c);
            float x1 = x[2*d], x2 = x[2*d+1];
            float a = x1 * c - x2 * s;
            float bb = x1 * s + x2 * c;
            ss = fmaf(a, a, fmaf(bb, bb, ss));
            o[d]      = f2bf(a);
            o[d + 32] = f2bf(bb);
        }
        #pragma unroll
        for (int i = 0; i < 8; i++) *(uint4*)(p + i * 8) = ((const uint4*)o)[i];
        dninv[h * 1024 + t] = DNSCALE * rsqrtf(fmaxf(ss, 1e-6f));
        return;
    }
    // V transpose: tile (h, tb): V[s0..+64][h*64..+64] -> VT[h][d][s0..+64]
    b -= 64;
    const int h = b >> 4, s0 = (b & 15) * 64;
    __shared__ unsigned short tile[64 * 64];   // [d][s-chunk ^ ((d^(d>>3))&7)]
    const unsigned short* V = qkv + 5120;
    const int pr = tid >> 3, cch = tid & 7;
    uint4 g0 = *(const uint4*)&V[(size_t)(s0 + 2 * pr)     * QKV_N + h * 64 + cch * 8];
    uint4 g1 = *(const uint4*)&V[(size_t)(s0 + 2 * pr + 1) * QKV_N + h * 64 + cch * 8];
    const unsigned short* p0 = (const unsigned short*)&g0;
    const unsigned short* p1 = (const unsigned short*)&g1;
    #pragma unroll
    for (int j = 0; j < 8; j++){
        int d = cch * 8 + j;
        int physc = (pr >> 2) ^ ((d ^ (d >> 3)) & 7);
        unsigned int val = (unsigned int)p0[j] | ((unsigned int)p1[j] << 16);
        ((unsigned int*)tile)[d * 32 + physc * 4 + (pr & 3)] = val;
    }
    __syncthreads();
    #pragma unroll
    for (int i = 0; i < 2; i++){
        int slot = tid + i * 256;
        int d = slot >> 3, c = slot & 7;
        int phys = c ^ ((d ^ (d >> 3)) & 7);
        uint4 v = *(const uint4*)&tile[d * 64 + phys * 8];
        *(uint4*)&VT[((size_t)h * 64 + d) * 1024 + s0 + c * 8] = v;
    }
}

// ---------------- fused attention (register-prefetch pipelined) ----------------
// grid (h 0..63, qy 0..15), qt = 15 - qy. 256 thr = 4 waves; wave w owns q rows [w*16,+16).
__global__ __launch_bounds__(256) void attn_mfma(
    const unsigned short* __restrict__ qkv,
    const unsigned short* __restrict__ VT,   // [64][64][1024]
    const float* __restrict__ dninv,
    const float* __restrict__ sinks, const float* __restrict__ vnulls,
    unsigned short* __restrict__ ctx)        // [64][1024][64] bf16
{
    __shared__ unsigned short ks[64 * 64];   // [s][chunk ^ (s&7)]
    __shared__ unsigned short vt[64 * 64];   // [d][chunk ^ (d&7)]
    __shared__ unsigned short ws[64][72];    // P [q][s]
    __shared__ float dl[64];
    __shared__ float dsum[4][16];

    const int tid  = threadIdx.x;
    const int wave = tid >> 6;          // 0..3
    const int lane = tid & 63;
    const int l15  = lane & 15;
    const int quad = lane >> 4;
    const int h  = blockIdx.x;
    const int kh = h & 15;
    const int qt = 15 - blockIdx.y;
    const int t0 = qt << 6;

    const unsigned short* Q  = qkv;
    const unsigned short* Kp = qkv + 4096;
    const unsigned short* Vh = VT + (size_t)h * 64 * 1024;

    // staging geometry: slot = tid + i*256 -> row = slot>>3, phys = slot&7,
    // global chunk c = phys ^ (row&7); LDS dest lane-linear (conflict-free b128)
    const int srow0 = tid >> 3,        sphy0 = tid & 7;
    const int srow1 = (tid + 256) >> 3, sphy1 = tid & 7;
    const int sc0 = sphy0 ^ (srow0 & 7);
    const int sc1 = sphy1 ^ (srow1 & 7);

    // Q fragment with fused RoPE (Q in global is un-roped).
    bf16x8 qf0, qf1;
    {
        const int t = t0 + wave * 16 + l15;
        const unsigned short* qp = Q + (size_t)t * QKV_N + h * 64 + quad * 16;
        uint4 r0 = *(const uint4*)qp;
        uint4 r1 = *(const uint4*)(qp + 8);
        unsigned short e[16];
        *(uint4*)&e[0] = r0; *(uint4*)&e[8] = r1;
        unsigned short o0[8], o1[8];
        #pragma unroll
        for (int j = 0; j < 8; j++){
            int dp = quad * 8 + j;
            float inv = EXP2(-(float)dp * 0.4152410118609203f);
            float s, c; __sincosf((float)t * inv, &s, &c);
            float x1 = bf2f(e[2*j]), x2 = bf2f(e[2*j+1]);
            o0[j] = f2bf(x1 * c - x2 * s);
            o1[j] = f2bf(x1 * s + x2 * c);
        }
        qf0 = *(const bf16x8*)o0;
        qf1 = *(const bf16x8*)o1;
    }

    f32x4 acc_o[4];
    #pragma unroll
    for (int i = 0; i < 4; i++) acc_o[i] = (f32x4){0.f, 0.f, 0.f, 0.f};
    float den = 0.f;                    // per-lane, q = wave*16 + l15
    const int q_glob = t0 + wave * 16 + l15;

    uint4 kr0, kr1, vr0, vr1;
    float dreg = 0.f;
    // prefetch st = 0
    {
        kr0 = *(const uint4*)&Kp[(size_t)srow0 * QKV_N + kh * 64 + sc0 * 8];
        kr1 = *(const uint4*)&Kp[(size_t)srow1 * QKV_N + kh * 64 + sc1 * 8];
        vr0 = *(const uint4*)&Vh[(size_t)srow0 * 1024 + sc0 * 8];
        vr1 = *(const uint4*)&Vh[(size_t)srow1 * 1024 + sc1 * 8];
        if (tid < 64) dreg = dninv[kh * 1024 + tid];
    }

    for (int st = 0; st <= qt; st++){
        const int s0 = st << 6;
        __syncthreads();                // previous iteration's LDS reads done

        // commit prefetched regs to LDS (lane-linear 16B writes)
        *(uint4*)&ks[(size_t)tid * 8]         = kr0;
        *(uint4*)&ks[(size_t)(tid + 256) * 8] = kr1;
        *(uint4*)&vt[(size_t)tid * 8]         = vr0;
        *(uint4*)&vt[(size_t)(tid + 256) * 8] = vr1;
        if (tid < 64) dl[tid] = dreg;

        // issue next tile's loads (latency hidden behind this tile's compute)
        if (st < qt){
            const int sn = (st + 1) << 6;
            kr0 = *(const uint4*)&Kp[(size_t)(sn + srow0) * QKV_N + kh * 64 + sc0 * 8];
            kr1 = *(const uint4*)&Kp[(size_t)(sn + srow1) * QKV_N + kh * 64 + sc1 * 8];
            vr0 = *(const uint4*)&Vh[(size_t)srow0 * 1024 + sn + sc0 * 8];
            vr1 = *(const uint4*)&Vh[(size_t)srow1 * 1024 + sn + sc1 * 8];
            if (tid < 64) dreg = dninv[kh * 1024 + sn + tid];
        }
        __syncthreads();                // staging visible

        const bool diag = (st == qt);

        // S^T: mfma(kf, qf) -> lane owns 4 consecutive s (quad*4+r) for q = l15
        #pragma unroll
        for (int nt = 0; nt < 4; nt++){
            const int sbase = nt * 16 + quad * 4;
            uint2* wp = (uint2*)&ws[wave * 16 + l15][sbase];
            if (diag && nt > wave){ *wp = (uint2){0u, 0u}; continue; }

            f32x4 sc = (f32x4){0.f, 0.f, 0.f, 0.f};
            {
                int srow = nt * 16 + l15;
                int ph0 = quad ^ (srow & 7);
                int ph1 = (4 + quad) ^ (srow & 7);
                bf16x8 kf0 = *(const bf16x8*)&ks[srow * 64 + ph0 * 8];
                bf16x8 kf1 = *(const bf16x8*)&ks[srow * 64 + ph1 * 8];
                sc = __builtin_amdgcn_mfma_f32_16x16x32_bf16(kf0, qf0, sc, 0, 0, 0);
                sc = __builtin_amdgcn_mfma_f32_16x16x32_bf16(kf1, qf1, sc, 0, 0, 0);
            }
            float da[4];
            *(float4*)da = *(const float4*)&dl[sbase];
            float w4[4];
            #pragma unroll
            for (int r = 0; r < 4; r++){
                float y = sc[r] * da[r];                      // x * log2(e)
                float p = EXP2(-fabsf(y));
                float u = fmaxf(y, 0.f) + LOG2(1.f + p);      // softplus * log2(e)
                float e3 = EXP2(-SILU_SCALE * u);             // == exp(-SCALE*softplus)
                float wv = __fdividef(LN2 * u, 1.f + e3);
                wv = (s0 + sbase + r <= q_glob) ? wv : 0.f;
                den += wv;
                w4[r] = wv;
            }
            uint2 pk;
            pk.x = pack_bf2(w4[0], w4[1]);
            pk.y = pack_bf2(w4[2], w4[3]);
            *wp = pk;
        }

        // PV (wave-private ws rows)
        {
            const int prow = wave * 16 + l15;
            bf16x8 pf0 = *(const bf16x8*)&ws[prow][quad * 8];
            bf16x8 pf1 = *(const bf16x8*)&ws[prow][32 + quad * 8];
            const bool skip_hi = diag && (wave <= 1);   // s>=32 all masked
            #pragma unroll
            for (int dt = 0; dt < 4; dt++){
                int d = dt * 16 + l15;
                int sw = d & 7;
                bf16x8 vf0 = *(const bf16x8*)&vt[d * 64 + (quad ^ sw) * 8];
                acc_o[dt] = __builtin_amdgcn_mfma_f32_16x16x32_bf16(pf0, vf0, acc_o[dt], 0, 0, 0);
                if (!skip_hi){
                    bf16x8 vf1 = *(const bf16x8*)&vt[d * 64 + ((4 + quad) ^ sw) * 8];
                    acc_o[dt] = __builtin_amdgcn_mfma_f32_16x16x32_bf16(pf1, vf1, acc_o[dt], 0, 0, 0);
                }
            }
        }
    }

    // denominator: reduce across quads (same q = l15), redistribute via LDS
    den += __shfl_xor(den, 16);
    den += __shfl_xor(den, 32);
    if (quad == 0) dsum[wave][l15] = den;
    float den4[4];
    *(float4*)den4 = *(const float4*)&dsum[wave][quad * 4];

    float sinkv = tanhf(sinks[h]) + 1e-6f;
    #pragma unroll
    for (int r = 0; r < 4; r++){
        int qg = t0 + wave * 16 + quad * 4 + r;
        float alpha = __fdividef(1.f, den4[r] + sinkv + 1e-6f);
        #pragma unroll
        for (int dt = 0; dt < 4; dt++){
            int d = dt * 16 + l15;
            float o = (acc_o[dt][r] + sinkv * vnulls[h * 64 + d]) * alpha;
            ctx[((size_t)h * 1024 + qg) * 64 + d] = f2bf(o);
        }
    }
}

// avg over 4 branches -> bf16 [t][nh*64+d], 8 elems/thread
__global__ void avg_kernel(const unsigned short* __restrict__ ctx, unsigned short* __restrict__ avg)
{
    int i8 = (blockIdx.x * 256 + threadIdx.x) * 8;   // 1M elements
    int t = i8 >> 10, c = i8 & 1023;
    int nh = c >> 6, d = c & 63;
    float s[8] = {};
    #pragma unroll
    for (int br = 0; br < 4; br++){
        uint4 v = *(const uint4*)&ctx[((size_t)(br * 16 + nh) * 1024 + t) * 64 + d];
        const unsigned short* p = (const unsigned short*)&v;
        #pragma unroll
        for (int j = 0; j < 8; j++) s[j] += bf2f(p[j]);
    }
    union { unsigned short u[8]; uint4 v; } o;
    #pragma unroll
    for (int j = 0; j < 8; j++) o.u[j] = f2bf(0.25f * s[j]);
    *(uint4*)&avg[i8] = o.v;
}

extern "C" void kernel_launch(void* const* d_in, const int* in_sizes, int n_in,
                              void* d_out, int out_size, void* d_ws, size_t ws_size,
                              hipStream_t stream)
{
    (void)in_sizes; (void)n_in; (void)out_size; (void)ws_size;
    const float* X      = (const float*)d_in[0];
    const float* Wq     = (const float*)d_in[1];
    const float* bq     = (const float*)d_in[2];
    const float* Wk     = (const float*)d_in[3];
    const float* bk     = (const float*)d_in[4];
    const float* Wv     = (const float*)d_in[5];
    const float* bv     = (const float*)d_in[6];
    const float* sinks  = (const float*)d_in[7];
    const float* vnulls = (const float*)d_in[8];
    const float* Wo     = (const float*)d_in[9];
    const float* bo     = (const float*)d_in[10];
    float* out = (float*)d_out;

    unsigned short* w16   = (unsigned short*)d_ws;
    unsigned short* Xb    = w16;                                  // 1M
    unsigned short* WqkvT = Xb    + (size_t)1024 * 1024;          // 9216*1024
    unsigned short* QKVb  = WqkvT + (size_t)QKV_N * 1024;         // 1024*9216
    unsigned short* WoT   = QKVb  + (size_t)1024 * QKV_N;         // 1M
    unsigned short* ctxb  = WoT   + (size_t)1024 * 1024;          // 4M
    unsigned short* avgb  = ctxb  + (size_t)64 * 1024 * 64;       // 1M
    float* qkvb = (float*)(avgb + (size_t)1024 * 1024);           // 9216
    float* dnf  = qkvb + QKV_N;                                   // 16*1024
    // WqkvT (18.9MB) is dead after gemm_qkv; reuse: VT (8MB) then pWo (8MB, after attn)
    unsigned short* VTb = WqkvT;                                  // 64*64*1024 bf16 = 8MB
    float* pWo = (float*)(WqkvT + (size_t)4 * 1024 * 1024);       // 8MB at +8MB offset

    dim3 blk(256);
    prep_kernel<<<3108, blk, 0, stream>>>(X, Wq, Wk, Wv, Wo, bq, bk, bv,
                                          Xb, WqkvT, WoT, qkvb);
    gemm_k<128, 96, 1><<<dim3(96, 8), blk, 0, stream>>>(Xb, WqkvT, qkvb, QKVb, 1024, QKV_N, 1024);
    postproc_kernel<<<1088, blk, 0, stream>>>(QKVb, dnf, VTb);
    attn_mfma<<<dim3(64, 16), blk, 0, stream>>>(QKVb, VTb, dnf, sinks, vnulls, ctxb);
    avg_kernel<<<512, blk, 0, stream>>>(ctxb, avgb);
    gemm_wo<<<dim3(16, 8, 2), blk, 0, stream>>>(avgb, WoT, pWo);
    wo_reduce<<<1024, blk, 0, stream>>>(pWo, bo, out);
}